// Round 6
// baseline (574.632 us; speedup 1.0000x reference)
//
#include <hip/hip_runtime.h>
#include <hip/hip_bf16.h>
#include <math.h>

#define NN   8192
#define TT   32
#define DIN  4096
#define MME  1024
#define NNZK 131072
#define EPSV 1e-5f
#define MALL (NN + MME)   // 9216 combined node+edge rows

typedef __attribute__((ext_vector_type(8))) short bf16x8;
typedef __attribute__((ext_vector_type(4))) float f32x4;

__device__ __forceinline__ float lrelu(float v){ return v > 0.f ? v : 0.2f*v; }
__device__ __forceinline__ short f2b(float f){
    union { __hip_bfloat16 h; short s; } u; u.h = __float2bfloat16(f); return u.s;
}
__device__ __forceinline__ float b2f(short s){
    union { float f; unsigned u; } u; u.u = ((unsigned)(unsigned short)s) << 16; return u.f;
}

// ---------------------------------------------------------------- utilities
__global__ void zero_i(int* p, int n){ int i = blockIdx.x*256 + threadIdx.x; if (i < n) p[i] = 0; }
__global__ void zero_f(float* p, int n){ int i = blockIdx.x*256 + threadIdx.x; if (i < n) p[i] = 0.f; }
__global__ void copy_i(const int* a, int* b, int n){ int i = blockIdx.x*256 + threadIdx.x; if (i < n) b[i] = a[i]; }

__global__ void count_seg(const int* __restrict__ he_n, const int* __restrict__ he_e,
                          int* __restrict__ ncnt, int* __restrict__ ecnt){
    int k = blockIdx.x*256 + threadIdx.x;
    if (k < NNZK){ atomicAdd(&ecnt[he_e[k]], 1); atomicAdd(&ncnt[he_n[k]], 1); }
}

// single-block exclusive scan, wave-shuffle based (n multiple of 1024; 2 barriers)
__global__ void scan_excl(const int* __restrict__ cnt, int* __restrict__ off, int n){
    int t = threadIdx.x;              // 1024 threads
    int lane = t & 63, wv = t >> 6;   // 16 waves
    int chunk = n >> 10;
    int base = t*chunk;
    int s = 0;
#pragma unroll 4
    for (int i = 0; i < chunk; i++) s += cnt[base+i];
    int v = s;
    for (int d = 1; d < 64; d <<= 1){
        int u = __shfl_up(v, d);
        if (lane >= d) v += u;
    }
    __shared__ int wsum[16];
    if (lane == 63) wsum[wv] = v;
    __syncthreads();
    if (wv == 0 && lane < 16){
        int w2 = wsum[lane];
        for (int d = 1; d < 16; d <<= 1){
            int u = __shfl_up(w2, d);
            if (lane >= d) w2 += u;
        }
        wsum[lane] = w2;
    }
    __syncthreads();
    int excl = v - s + (wv > 0 ? wsum[wv-1] : 0);
    for (int i = 0; i < chunk; i++){
        off[base+i] = excl;
        excl += cnt[base+i];
    }
    if (t == 1023) off[n] = excl;
}

__global__ void fill_perm(const int* __restrict__ seg, int* __restrict__ cur, int* __restrict__ perm){
    int k = blockIdx.x*256 + threadIdx.x;
    if (k < NNZK){ int p = atomicAdd(&cur[seg[k]], 1); perm[p] = k; }
}

// ------------------------------------------------ weight convert + transpose
__global__ void wconv_t(const float* __restrict__ W, __hip_bfloat16* __restrict__ BT, int K, int N){
    __shared__ float tile[32][33];
    int k0 = blockIdx.y*32, n0 = blockIdx.x*32;
    int tx = threadIdx.x & 31, ty = threadIdx.x >> 5;
    for (int i = ty; i < 32; i += 8) tile[i][tx] = W[(size_t)(k0+i)*N + n0+tx];
    __syncthreads();
    for (int i = ty; i < 32; i += 8)
        BT[(size_t)(n0+i)*K + k0 + tx] = __float2bfloat16(tile[tx][i]);
}

#define SWZ(b) ((b) ^ ((((b) >> 6) & 7) << 4))

// ---------------------------------------------------------------- MFMA GEMM (swapped orientation)
// C[M,N] = Aact[M,K] @ Bwt^T, Bwt given as [N,K] bf16.
// Lane's f32x4 acc covers 4 CONSECUTIVE output columns -> vector stores.
// MODE 0: plain fp32 store
// MODE 3: lrelu(acc + bias[col]) -> bf16 store
// MODE 4: bf16 store to split-K slice blockIdx.z, PLUS store staged A as bf16 to xb
template<int MODE>
__global__ __launch_bounds__(256) void gemm_nt(
    const float* __restrict__ Aact, const __hip_bfloat16* __restrict__ Bwt,
    float* __restrict__ C, __hip_bfloat16* __restrict__ Cb, const float* __restrict__ bias,
    __hip_bfloat16* __restrict__ xb, int M, int N, int K, int kchunk)
{
    __shared__ f32x4 WsRaw[512];   // 8 KB
    __shared__ f32x4 XsRaw[512];   // 8 KB
    char* Ws = (char*)WsRaw;
    char* Xs = (char*)XsRaw;
    const int tid = threadIdx.x;
    const int lane = tid & 63;
    const int w = tid >> 6;
    const int m0 = blockIdx.y << 7, n0 = blockIdx.x << 7;
    const int kz = blockIdx.z * kchunk;
    const int wN = (w >> 1) << 6, wM = (w & 1) << 6;

    const int s0 = tid, s1 = tid + 256;
    const int r0 = s0 >> 2, k0b = (s0 & 3) << 3;
    const int r1 = s1 >> 2, k1b = (s1 & 3) << 3;
    const float* pX0 = Aact + (size_t)(m0 + r0)*K + kz + k0b;
    const float* pX1 = Aact + (size_t)(m0 + r1)*K + kz + k1b;
    const __hip_bfloat16* pW0 = Bwt + (size_t)(n0 + r0)*K + kz + k0b;
    const __hip_bfloat16* pW1 = Bwt + (size_t)(n0 + r1)*K + kz + k1b;
    __hip_bfloat16* pXB0 = xb + (size_t)(m0 + r0)*K + kz + k0b;
    __hip_bfloat16* pXB1 = xb + (size_t)(m0 + r1)*K + kz + k1b;
    const int wo0 = SWZ(s0 << 4), wo1 = SWZ(s1 << 4);

    int rwOff[4], rxOff[4];
#pragma unroll
    for (int f = 0; f < 4; f++){
        rwOff[f] = SWZ((wN + f*16 + (lane & 15))*64 + ((lane >> 4) << 4));
        rxOff[f] = SWZ((wM + f*16 + (lane & 15))*64 + ((lane >> 4) << 4));
    }

    f32x4 acc[4][4] = {};

    float4 x0l = *(const float4*)pX0, x0h = *(const float4*)(pX0+4);
    float4 x1l = *(const float4*)pX1, x1h = *(const float4*)(pX1+4);
    bf16x8 w0 = *(const bf16x8*)pW0, w1 = *(const bf16x8*)pW1;

    const int nsteps = kchunk >> 5;
    for (int ks = 0; ks < nsteps; ks++){
        bf16x8 vx0, vx1;
        vx0[0]=f2b(x0l.x); vx0[1]=f2b(x0l.y); vx0[2]=f2b(x0l.z); vx0[3]=f2b(x0l.w);
        vx0[4]=f2b(x0h.x); vx0[5]=f2b(x0h.y); vx0[6]=f2b(x0h.z); vx0[7]=f2b(x0h.w);
        vx1[0]=f2b(x1l.x); vx1[1]=f2b(x1l.y); vx1[2]=f2b(x1l.z); vx1[3]=f2b(x1l.w);
        vx1[4]=f2b(x1h.x); vx1[5]=f2b(x1h.y); vx1[6]=f2b(x1h.z); vx1[7]=f2b(x1h.w);
        if (MODE == 4){
            *(bf16x8*)(pXB0 + ks*32) = vx0;
            *(bf16x8*)(pXB1 + ks*32) = vx1;
        }
        __syncthreads();
        *(bf16x8*)(Xs + wo0) = vx0;
        *(bf16x8*)(Xs + wo1) = vx1;
        *(bf16x8*)(Ws + wo0) = w0;
        *(bf16x8*)(Ws + wo1) = w1;
        __syncthreads();
        if (ks + 1 < nsteps){
            pX0 += 32; pX1 += 32; pW0 += 32; pW1 += 32;
            x0l = *(const float4*)pX0; x0h = *(const float4*)(pX0+4);
            x1l = *(const float4*)pX1; x1h = *(const float4*)(pX1+4);
            w0 = *(const bf16x8*)pW0;  w1 = *(const bf16x8*)pW1;
        }
        bf16x8 wf[4], xf[4];
#pragma unroll
        for (int f = 0; f < 4; f++){
            wf[f] = *(const bf16x8*)(Ws + rwOff[f]);
            xf[f] = *(const bf16x8*)(Xs + rxOff[f]);
        }
#pragma unroll
        for (int i = 0; i < 4; i++)
#pragma unroll
            for (int j = 0; j < 4; j++)
                acc[i][j] = __builtin_amdgcn_mfma_f32_16x16x32_bf16(wf[i], xf[j], acc[i][j], 0, 0, 0);
    }

    const int mc = wM + (lane & 15);
    const int ncb = wN + ((lane >> 4) << 2);
#pragma unroll
    for (int j = 0; j < 4; j++){
        int row = m0 + mc + j*16;
#pragma unroll
        for (int i = 0; i < 4; i++){
            int col = n0 + ncb + i*16;
            f32x4 v = acc[i][j];
            if (MODE == 0){
                *(float4*)&C[(size_t)row*N + col] = *(float4*)&v;
            } else if (MODE == 4){
                __hip_bfloat16* Cz = Cb + (size_t)blockIdx.z * ((size_t)M * (size_t)N);
                short4 sv = { f2b(v[0]), f2b(v[1]), f2b(v[2]), f2b(v[3]) };
                *(short4*)&Cz[(size_t)row*N + col] = sv;
            } else {  // MODE 3
                float4 b4 = *(const float4*)&bias[col];
                short4 sv = { f2b(lrelu(v[0] + b4.x)), f2b(lrelu(v[1] + b4.y)),
                              f2b(lrelu(v[2] + b4.z)), f2b(lrelu(v[3] + b4.w)) };
                *(short4*)&Cb[(size_t)row*N + col] = sv;
            }
        }
    }
}

// split-K reduce (bf16 partials) + bias + lrelu + fused BN stats (row length 128 floats)
__global__ void reduce8s(const __hip_bfloat16* __restrict__ part, const float* __restrict__ bias,
                         float* __restrict__ out, int nf4, int parts, float* __restrict__ slots){
    int tid = threadIdx.x;
    int i = blockIdx.x*256 + tid;
    const short4* p4 = (const short4*)part;
    short4 v0 = p4[i];
    float4 s = { b2f(v0.x), b2f(v0.y), b2f(v0.z), b2f(v0.w) };
    for (int z = 1; z < parts; z++){
        short4 p = p4[(size_t)z*nf4 + i];
        s.x += b2f(p.x); s.y += b2f(p.y); s.z += b2f(p.z); s.w += b2f(p.w);
    }
    int c0 = (i & 31) << 2;
    s.x = lrelu(s.x + bias[c0+0]); s.y = lrelu(s.y + bias[c0+1]);
    s.z = lrelu(s.z + bias[c0+2]); s.w = lrelu(s.w + bias[c0+3]);
    ((float4*)out)[i] = s;
    __shared__ float S[128], Q[128];
    if (tid < 128){ S[tid] = 0.f; Q[tid] = 0.f; }
    __syncthreads();
    atomicAdd(&S[c0+0], s.x); atomicAdd(&Q[c0+0], s.x*s.x);
    atomicAdd(&S[c0+1], s.y); atomicAdd(&Q[c0+1], s.y*s.y);
    atomicAdd(&S[c0+2], s.z); atomicAdd(&Q[c0+2], s.z*s.z);
    atomicAdd(&S[c0+3], s.w); atomicAdd(&Q[c0+3], s.w*s.w);
    __syncthreads();
    if (tid < 128){
        int slot = blockIdx.x & 31;
        atomicAdd(&slots[slot*256 + tid], S[tid]);
        atomicAdd(&slots[slot*256 + 128 + tid], Q[tid]);
    }
}

// ---------------------------------------------------------------- final stage streaming (all bf16 reads)
__global__ __launch_bounds__(256) void final_stats(
    const bf16x8* __restrict__ xb, const bf16x8* __restrict__ f,
    float* __restrict__ slots, int n8)
{
    int tid = threadIdx.x;
    float s[8] = {0,0,0,0,0,0,0,0}, q[8] = {0,0,0,0,0,0,0,0};
    int stride = gridDim.x*256;
    for (int i = blockIdx.x*256 + tid; i < n8; i += stride){
        bf16x8 xv = xb[i], fv = f[i];
#pragma unroll
        for (int j = 0; j < 8; j++){
            float y = b2f(xv[j]) + b2f(fv[j]);
            s[j] += y; q[j] += y*y;
        }
    }
    __shared__ float S[128], Q[128];
    if (tid < 128){ S[tid] = 0.f; Q[tid] = 0.f; }
    __syncthreads();
    int c0 = (tid & 15) << 3;
#pragma unroll
    for (int j = 0; j < 8; j++){
        atomicAdd(&S[c0+j], s[j]);
        atomicAdd(&Q[c0+j], q[j]);
    }
    __syncthreads();
    if (tid < 128){
        int slot = blockIdx.x & 31;
        atomicAdd(&slots[slot*256 + tid], S[tid]);
        atomicAdd(&slots[slot*256 + 128 + tid], Q[tid]);
    }
}

__global__ __launch_bounds__(256) void final_apply(
    const bf16x8* __restrict__ xb, const bf16x8* __restrict__ f,
    const float* __restrict__ coef, float4* __restrict__ out, int n8)
{
    int tid = threadIdx.x;
    int c0 = (tid & 15) << 3;
    float sc[8], sh[8];
#pragma unroll
    for (int j = 0; j < 8; j++){ sc[j] = coef[c0+j]; sh[j] = coef[128+c0+j]; }
    int stride = gridDim.x*256;
    for (int i = blockIdx.x*256 + tid; i < n8; i += stride){
        bf16x8 xv = xb[i], fv = f[i];
        float4 lo, hi;
        lo.x = (b2f(xv[0]) + b2f(fv[0]))*sc[0] + sh[0];
        lo.y = (b2f(xv[1]) + b2f(fv[1]))*sc[1] + sh[1];
        lo.z = (b2f(xv[2]) + b2f(fv[2]))*sc[2] + sh[2];
        lo.w = (b2f(xv[3]) + b2f(fv[3]))*sc[3] + sh[3];
        hi.x = (b2f(xv[4]) + b2f(fv[4]))*sc[4] + sh[4];
        hi.y = (b2f(xv[5]) + b2f(fv[5]))*sc[5] + sh[5];
        hi.z = (b2f(xv[6]) + b2f(fv[6]))*sc[6] + sh[6];
        hi.w = (b2f(xv[7]) + b2f(fv[7]))*sc[7] + sh[7];
        out[2*i]   = lo;
        out[2*i+1] = hi;
    }
}

// ---------------------------------------------------------------- BatchNorm
__global__ void bn_stats_v2(const float* __restrict__ x, float* __restrict__ slots, int rows){
    int cg = threadIdx.x & 31, rg = threadIdx.x >> 5;
    float4 s = {0,0,0,0}, q = {0,0,0,0};
    for (int r = blockIdx.x*8 + rg; r < rows; r += gridDim.x*8){
        float4 v = ((const float4*)x)[(size_t)r*32 + cg];
        s.x += v.x; q.x += v.x*v.x;
        s.y += v.y; q.y += v.y*v.y;
        s.z += v.z; q.z += v.z*v.z;
        s.w += v.w; q.w += v.w*v.w;
    }
    __shared__ float S[128], Q[128];
    if (threadIdx.x < 128){ S[threadIdx.x] = 0.f; Q[threadIdx.x] = 0.f; }
    __syncthreads();
    int c0 = cg << 2;
    atomicAdd(&S[c0+0], s.x); atomicAdd(&Q[c0+0], q.x);
    atomicAdd(&S[c0+1], s.y); atomicAdd(&Q[c0+1], q.y);
    atomicAdd(&S[c0+2], s.z); atomicAdd(&Q[c0+2], q.z);
    atomicAdd(&S[c0+3], s.w); atomicAdd(&Q[c0+3], q.w);
    __syncthreads();
    if (threadIdx.x < 128){
        int slot = blockIdx.x & 31;
        atomicAdd(&slots[slot*256 + threadIdx.x], S[threadIdx.x]);
        atomicAdd(&slots[slot*256 + 128 + threadIdx.x], Q[threadIdx.x]);
    }
}

__global__ void bn_finalize2(const float* __restrict__ slots, int nslots,
                             const float* __restrict__ g, const float* __restrict__ b,
                             float invR, float* __restrict__ coef){
    int c = threadIdx.x;
    float s = 0.f, q = 0.f;
    for (int k = 0; k < nslots; k++){ s += slots[k*256 + c]; q += slots[k*256 + 128 + c]; }
    float m = s*invR;
    float v = q*invR - m*m;
    float sc = g[c]*rsqrtf(v + EPSV);
    coef[c] = sc;
    coef[128 + c] = b[c] - m*sc;
}

__global__ void bn_apply4(float4* __restrict__ x, const float* __restrict__ coef, size_t n4){
    size_t i = (size_t)blockIdx.x*blockDim.x + threadIdx.x;
    size_t stride = (size_t)gridDim.x*blockDim.x;
    for (; i < n4; i += stride){
        int c0 = (int)(i & 31) * 4;
        float4 v = x[i];
        v.x = v.x*coef[c0+0] + coef[128+c0+0];
        v.y = v.y*coef[c0+1] + coef[128+c0+1];
        v.z = v.z*coef[c0+2] + coef[128+c0+2];
        v.w = v.w*coef[c0+3] + coef[128+c0+3];
        x[i] = v;
    }
}

// ---------------------------------------------------------------- segment ops
__global__ void seg_sum_edge(const int* __restrict__ eoff, const int* __restrict__ eperm,
                             const int* __restrict__ he_n, const float* __restrict__ h,
                             float* __restrict__ out){
    int m = blockIdx.x, c = threadIdx.x;
    int s0 = eoff[m], cnt = eoff[m+1] - s0;
    __shared__ int sn[128];
    float acc = 0.f;
    for (int base = 0; base < cnt; base += 128){
        int i = base + c;
        if (i < cnt) sn[c] = he_n[eperm[s0+i]];
        __syncthreads();
        int lim = min(128, cnt - base);
        for (int j = 0; j < lim; j++) acc += h[(size_t)sn[j]*128 + c];
        __syncthreads();
    }
    out[(size_t)m*128 + c] = acc;
}

template<int H>
__global__ void row_att(const float* __restrict__ xt, const float* __restrict__ att,
                        int aoff, float* __restrict__ out){
    int n = blockIdx.x, lane = threadIdx.x;
#pragma unroll
    for (int h = 0; h < H; h++){
        const float* xr = xt + (size_t)n*(H*128) + h*128;
        const float* ar = att + h*256 + aoff;
        float s = xr[lane]*ar[lane] + xr[lane+64]*ar[lane+64];
        for (int d = 32; d > 0; d >>= 1) s += __shfl_down(s, d);
        if (lane == 0) out[n*H + h] = s;
    }
}

template<int H>
__global__ void seg_softmax(const int* __restrict__ eoff, const int* __restrict__ eperm,
                            const int* __restrict__ he_n,
                            const float* __restrict__ ax, const float* __restrict__ ae,
                            float* __restrict__ alpha){
    int m = blockIdx.x, t = threadIdx.x;
    int s0 = eoff[m], cnt = eoff[m+1] - s0;
    if (cnt == 0) return;
    __shared__ float red[128];
    float aeh[H];
#pragma unroll
    for (int h = 0; h < H; h++) aeh[h] = ae[m*H + h];
    float lmax[H];
#pragma unroll
    for (int h = 0; h < H; h++) lmax[h] = -1e30f;
    for (int i = t; i < cnt; i += 128){
        int k = eperm[s0+i]; int n = he_n[k];
#pragma unroll
        for (int h = 0; h < H; h++){
            float v = lrelu(ax[n*H + h] + aeh[h]);
            alpha[(size_t)k*H + h] = v;
            lmax[h] = fmaxf(lmax[h], v);
        }
    }
    float gmax[H];
#pragma unroll
    for (int h = 0; h < H; h++){
        red[t] = lmax[h]; __syncthreads();
        for (int s = 64; s > 0; s >>= 1){ if (t < s) red[t] = fmaxf(red[t], red[t+s]); __syncthreads(); }
        gmax[h] = red[0]; __syncthreads();
    }
    float lsum[H];
#pragma unroll
    for (int h = 0; h < H; h++) lsum[h] = 0.f;
    for (int i = t; i < cnt; i += 128){
        int k = eperm[s0+i];
#pragma unroll
        for (int h = 0; h < H; h++){
            float ex = __expf(alpha[(size_t)k*H + h] - gmax[h]);
            alpha[(size_t)k*H + h] = ex;
            lsum[h] += ex;
        }
    }
    float ginv[H];
#pragma unroll
    for (int h = 0; h < H; h++){
        red[t] = lsum[h]; __syncthreads();
        for (int s = 64; s > 0; s >>= 1){ if (t < s) red[t] += red[t+s]; __syncthreads(); }
        ginv[h] = 1.f/red[0]; __syncthreads();
    }
    for (int i = t; i < cnt; i += 128){
        int k = eperm[s0+i];
#pragma unroll
        for (int h = 0; h < H; h++) alpha[(size_t)k*H + h] *= ginv[h];
    }
}

__global__ void seg_eo4(const int* __restrict__ eoff, const int* __restrict__ eperm,
                        const int* __restrict__ he_n,
                        const float* __restrict__ alpha, const float* __restrict__ xt,
                        float* __restrict__ eo){
    int m = blockIdx.x;
    int c = threadIdx.x & 127, hb = threadIdx.x >> 7;   // hb in {0,1}
    int s0 = eoff[m], cnt = eoff[m+1] - s0;
    __shared__ int sn[128];
    __shared__ float sa[128][4];
    float acc0 = 0.f, acc1 = 0.f;
    for (int base = 0; base < cnt; base += 128){
        int i = base + threadIdx.x;
        if (threadIdx.x < 128 && i < cnt){
            int k = eperm[s0+i];
            sn[threadIdx.x] = he_n[k];
#pragma unroll
            for (int h = 0; h < 4; h++) sa[threadIdx.x][h] = alpha[(size_t)k*4 + h];
        }
        __syncthreads();
        int lim = min(128, cnt - base);
        for (int j = 0; j < lim; j++){
            const float* xr = xt + (size_t)sn[j]*512;
            acc0 += sa[j][hb]   * xr[hb*128 + c];
            acc1 += sa[j][hb+2] * xr[(hb+2)*128 + c];
        }
        __syncthreads();
    }
    float binv = cnt > 0 ? 1.f/(float)cnt : 0.f;
    eo[(size_t)m*512 + hb*128 + c]     = acc0*binv;
    eo[(size_t)m*512 + (hb+2)*128 + c] = acc1*binv;
}

__global__ void seg_eo1(const int* __restrict__ eoff, const int* __restrict__ eperm,
                        const int* __restrict__ he_n,
                        const float* __restrict__ alpha, const float* __restrict__ xt,
                        float* __restrict__ eo){
    int m = blockIdx.x, c = threadIdx.x;
    int s0 = eoff[m], cnt = eoff[m+1] - s0;
    __shared__ int sn[128];
    __shared__ float sa[128];
    float acc = 0.f;
    for (int base = 0; base < cnt; base += 128){
        int i = base + c;
        if (i < cnt){
            int k = eperm[s0+i];
            sn[c] = he_n[k];
            sa[c] = alpha[k];
        }
        __syncthreads();
        int lim = min(128, cnt - base);
        for (int j = 0; j < lim; j++) acc += sa[j]*xt[(size_t)sn[j]*128 + c];
        __syncthreads();
    }
    float binv = cnt > 0 ? 1.f/(float)cnt : 0.f;
    eo[(size_t)m*128 + c] = acc*binv;
}

template<int H>
__global__ void seg_node_out(const int* __restrict__ noff, const int* __restrict__ nperm,
                             const int* __restrict__ he_e,
                             const float* __restrict__ alpha, const float* __restrict__ eo,
                             const float* __restrict__ hin, const float* __restrict__ bias,
                             float* __restrict__ hout){
    int n = blockIdx.x, c = threadIdx.x;
    int s0 = noff[n], cnt = noff[n+1] - s0;
    float acc = 0.f;
    for (int i = 0; i < cnt; i++){
        int k = nperm[s0+i]; int e = he_e[k];
        const float* er = eo + (size_t)e*(128*H);
#pragma unroll
        for (int h = 0; h < H; h++) acc += alpha[(size_t)k*H + h]*er[h*128 + c];
    }
    float dinv = cnt > 0 ? 1.f/((float)cnt*(float)H) : 0.f;
    hout[(size_t)n*128 + c] = hin[(size_t)n*128 + c] + bias[c] + acc*dinv;
}

// ---------------------------------------------------------------- launcher
extern "C" void kernel_launch(void* const* d_in, const int* in_sizes, int n_in,
                              void* d_out, int out_size, void* d_ws, size_t ws_size,
                              hipStream_t stream){
    const float* x    = (const float*)d_in[0];
    const int*   he_n = (const int*)  d_in[1];
    const int*   he_e = (const int*)  d_in[2];
    const float* W1   = (const float*)d_in[3];
    const float* b1   = (const float*)d_in[4];
    const float* g1   = (const float*)d_in[5];
    const float* be1  = (const float*)d_in[6];
    const float* Wh1  = (const float*)d_in[7];
    const float* att1 = (const float*)d_in[8];
    const float* bh1  = (const float*)d_in[9];
    const float* g2   = (const float*)d_in[10];
    const float* be2  = (const float*)d_in[11];
    const float* Wh2  = (const float*)d_in[12];
    const float* att2 = (const float*)d_in[13];
    const float* bh2  = (const float*)d_in[14];
    const float* g3   = (const float*)d_in[15];
    const float* be3  = (const float*)d_in[16];
    const float* W3   = (const float*)d_in[17];
    const float* b3   = (const float*)d_in[18];
    const float* g4   = (const float*)d_in[19];
    const float* be4  = (const float*)d_in[20];
    float* out = (float*)d_out;

    char* ws = (char*)d_ws;
    size_t off = 0;
    auto alloc = [&](size_t bytes)->char*{ char* p = ws + off; off += (bytes + 255) & ~(size_t)255; return p; };

    // big region (64 MB): fbuf (final stage) aliases part (GEMM1 stage) + xt1 (hconv1 stage)
    char* big = alloc((size_t)NN*DIN*2);
    __hip_bfloat16* fbuf = (__hip_bfloat16*)big;
    __hip_bfloat16* part = (__hip_bfloat16*)big;                       // 16 slices x 2MB = 32MB
    float*          xt1  = (float*)(big + (size_t)16*NN*128*2);        // 18.9MB at +32MB (fits in 64MB)
    __hip_bfloat16* xbuf = (__hip_bfloat16*)alloc((size_t)NN*DIN*2);   // bf16 copy of x (64MB), lives whole pass

    float* hall1  = (float*)alloc((size_t)MALL*128*4);
    float* hall2  = (float*)alloc((size_t)MALL*128*4);
    float* h3     = (float*)alloc((size_t)NN*128*4);
    float* xt2    = (float*)alloc((size_t)MALL*128*4);
    float* eo     = (float*)alloc((size_t)MME*512*4);
    float* alpha  = (float*)alloc((size_t)NNZK*4*4);
    float* ax     = (float*)alloc((size_t)NN*4*4);
    float* ae     = (float*)alloc((size_t)MME*4*4);
    float* slots  = (float*)alloc((size_t)32*256*4);
    float* coef   = (float*)alloc(256*4);
    __hip_bfloat16* W1T  = (__hip_bfloat16*)alloc((size_t)128*DIN*2);
    __hip_bfloat16* Wh1T = (__hip_bfloat16*)alloc((size_t)512*128*2);
    __hip_bfloat16* Wh2T = (__hip_bfloat16*)alloc((size_t)128*128*2);
    __hip_bfloat16* W3T  = (__hip_bfloat16*)alloc((size_t)DIN*128*2);
    int* ecnt  = (int*)alloc(MME*4);
    int* ncnt  = (int*)alloc(NN*4);
    int* eoffb = (int*)alloc((MME+1)*4);
    int* ecur  = (int*)alloc(MME*4);
    int* noffb = (int*)alloc((NN+1)*4);
    int* ncur  = (int*)alloc(NN*4);
    int* eperm = (int*)alloc((size_t)NNZK*4);
    int* nperm = (int*)alloc((size_t)NNZK*4);

    // ---- CSR build ----
    zero_i<<<(MME+NN+255)/256, 256, 0, stream>>>(ecnt, MME+NN);   // ecnt+ncnt adjacent
    count_seg<<<NNZK/256, 256, 0, stream>>>(he_n, he_e, ncnt, ecnt);
    scan_excl<<<1, 1024, 0, stream>>>(ecnt, eoffb, MME);
    scan_excl<<<1, 1024, 0, stream>>>(ncnt, noffb, NN);
    copy_i<<<(MME+255)/256, 256, 0, stream>>>(eoffb, ecur, MME);
    copy_i<<<(NN+255)/256, 256, 0, stream>>>(noffb, ncur, NN);
    fill_perm<<<NNZK/256, 256, 0, stream>>>(he_e, ecur, eperm);
    fill_perm<<<NNZK/256, 256, 0, stream>>>(he_n, ncur, nperm);

    // ---- weight transpose+convert ----
    wconv_t<<<dim3(128/32, DIN/32), 256, 0, stream>>>(W1,  W1T,  DIN, 128);
    wconv_t<<<dim3(512/32, 128/32), 256, 0, stream>>>(Wh1, Wh1T, 128, 512);
    wconv_t<<<dim3(128/32, 128/32), 256, 0, stream>>>(Wh2, Wh2T, 128, 128);
    wconv_t<<<dim3(DIN/32, 128/32), 256, 0, stream>>>(W3,  W3T,  128, DIN);

    // ---- layer 0: h1 = lrelu(x @ W1 + b1); BN1; side-product xbuf = bf16(x) ----
    gemm_nt<4><<<dim3(1, NN/128, 16), 256, 0, stream>>>(x, W1T, nullptr, part, nullptr, xbuf, NN, 128, DIN, DIN/16);
    zero_f<<<32, 256, 0, stream>>>(slots, 32*256);
    reduce8s<<<NN*128/4/256, 256, 0, stream>>>(part, b1, hall1, NN*128/4, 16, slots);
    bn_finalize2<<<1, 128, 0, stream>>>(slots, 32, g1, be1, 1.f/NN, coef);
    bn_apply4<<<1024, 256, 0, stream>>>((float4*)hall1, coef, (size_t)NN*32);

    // ---- hconv1 (heads=4) ----
    seg_sum_edge<<<MME, 128, 0, stream>>>(eoffb, eperm, he_n, hall1, hall1 + (size_t)NN*128);
    gemm_nt<0><<<dim3(512/128, MALL/128, 1), 256, 0, stream>>>(hall1, Wh1T, xt1, nullptr, nullptr, nullptr, MALL, 512, 128, 128);
    row_att<4><<<NN, 64, 0, stream>>>(xt1, att1, 0, ax);
    row_att<4><<<MME, 64, 0, stream>>>(xt1 + (size_t)NN*512, att1, 128, ae);
    seg_softmax<4><<<MME, 128, 0, stream>>>(eoffb, eperm, he_n, ax, ae, alpha);
    seg_eo4<<<MME, 256, 0, stream>>>(eoffb, eperm, he_n, alpha, xt1, eo);
    seg_node_out<4><<<NN, 128, 0, stream>>>(noffb, nperm, he_e, alpha, eo, hall1, bh1, hall2);
    zero_f<<<32, 256, 0, stream>>>(slots, 32*256);
    bn_stats_v2<<<256, 256, 0, stream>>>(hall2, slots, NN);
    bn_finalize2<<<1, 128, 0, stream>>>(slots, 32, g2, be2, 1.f/NN, coef);
    bn_apply4<<<1024, 256, 0, stream>>>((float4*)hall2, coef, (size_t)NN*32);

    // ---- hconv2 (heads=1) ----
    seg_sum_edge<<<MME, 128, 0, stream>>>(eoffb, eperm, he_n, hall2, hall2 + (size_t)NN*128);
    gemm_nt<0><<<dim3(1, MALL/128, 1), 256, 0, stream>>>(hall2, Wh2T, xt2, nullptr, nullptr, nullptr, MALL, 128, 128, 128);
    row_att<1><<<NN, 64, 0, stream>>>(xt2, att2, 0, ax);
    row_att<1><<<MME, 64, 0, stream>>>(xt2 + (size_t)NN*128, att2, 128, ae);
    seg_softmax<1><<<MME, 128, 0, stream>>>(eoffb, eperm, he_n, ax, ae, alpha);
    seg_eo1<<<MME, 128, 0, stream>>>(eoffb, eperm, he_n, alpha, xt2, eo);
    seg_node_out<1><<<NN, 128, 0, stream>>>(noffb, nperm, he_e, alpha, eo, hall2, bh2, h3);
    zero_f<<<32, 256, 0, stream>>>(slots, 32*256);
    bn_stats_v2<<<256, 256, 0, stream>>>(h3, slots, NN);
    bn_finalize2<<<1, 128, 0, stream>>>(slots, 32, g3, be3, 1.f/NN, coef);
    bn_apply4<<<1024, 256, 0, stream>>>((float4*)h3, coef, (size_t)NN*32);

    // ---- final: out = BN4(x + lrelu(h3 @ W3 + b3)) ----
    // 1) f = lrelu(h3@W3+b3) -> bf16 (compute-only GEMM, light write)
    gemm_nt<3><<<dim3(DIN/128, NN/128, 1), 256, 0, stream>>>(h3, W3T, nullptr, fbuf, b3, nullptr, NN, DIN, 128, 128);
    // 2) streaming stats over y = xb + f (both bf16: 128 MB total)
    zero_f<<<32, 256, 0, stream>>>(slots, 32*256);
    final_stats<<<2048, 256, 0, stream>>>((const bf16x8*)xbuf, (const bf16x8*)fbuf, slots, NN*DIN/8);
    bn_finalize2<<<1, 128, 0, stream>>>(slots, 32, g4, be4, 1.f/((float)NN*TT), coef);
    // 3) streaming apply (reads L3-hot xb/f, writes 128 MB out)
    final_apply<<<2048, 256, 0, stream>>>((const bf16x8*)xbuf, (const bf16x8*)fbuf, coef, (float4*)out, NN*DIN/8);
}

// Round 7
// 556.768 us; speedup vs baseline: 1.0321x; 1.0321x over previous
//
#include <hip/hip_runtime.h>
#include <hip/hip_bf16.h>
#include <math.h>

#define NN   8192
#define TT   32
#define DIN  4096
#define MME  1024
#define NNZK 131072
#define EPSV 1e-5f
#define MALL (NN + MME)   // 9216 combined node+edge rows

typedef __attribute__((ext_vector_type(8))) short bf16x8;
typedef __attribute__((ext_vector_type(4))) float f32x4;

__device__ __forceinline__ float lrelu(float v){ return v > 0.f ? v : 0.2f*v; }
__device__ __forceinline__ short f2b(float f){
    union { __hip_bfloat16 h; short s; } u; u.h = __float2bfloat16(f); return u.s;
}
__device__ __forceinline__ float b2f(short s){
    union { float f; unsigned u; } u; u.u = ((unsigned)(unsigned short)s) << 16; return u.f;
}

// ---------------------------------------------------------------- utilities
__global__ void zero_i(int* p, int n){ int i = blockIdx.x*256 + threadIdx.x; if (i < n) p[i] = 0; }
__global__ void zero_f(float* p, int n){ int i = blockIdx.x*256 + threadIdx.x; if (i < n) p[i] = 0.f; }
__global__ void copy_i(const int* a, int* b, int n){ int i = blockIdx.x*256 + threadIdx.x; if (i < n) b[i] = a[i]; }

__global__ void count_seg(const int* __restrict__ he_n, const int* __restrict__ he_e,
                          int* __restrict__ ncnt, int* __restrict__ ecnt){
    int k = blockIdx.x*256 + threadIdx.x;
    if (k < NNZK){ atomicAdd(&ecnt[he_e[k]], 1); atomicAdd(&ncnt[he_n[k]], 1); }
}

// single-block exclusive scan, wave-shuffle based (n multiple of 1024; 2 barriers)
__global__ void scan_excl(const int* __restrict__ cnt, int* __restrict__ off, int n){
    int t = threadIdx.x;              // 1024 threads
    int lane = t & 63, wv = t >> 6;   // 16 waves
    int chunk = n >> 10;
    int base = t*chunk;
    int s = 0;
#pragma unroll 4
    for (int i = 0; i < chunk; i++) s += cnt[base+i];
    int v = s;
    for (int d = 1; d < 64; d <<= 1){
        int u = __shfl_up(v, d);
        if (lane >= d) v += u;
    }
    __shared__ int wsum[16];
    if (lane == 63) wsum[wv] = v;
    __syncthreads();
    if (wv == 0 && lane < 16){
        int w2 = wsum[lane];
        for (int d = 1; d < 16; d <<= 1){
            int u = __shfl_up(w2, d);
            if (lane >= d) w2 += u;
        }
        wsum[lane] = w2;
    }
    __syncthreads();
    int excl = v - s + (wv > 0 ? wsum[wv-1] : 0);
    for (int i = 0; i < chunk; i++){
        off[base+i] = excl;
        excl += cnt[base+i];
    }
    if (t == 1023) off[n] = excl;
}

__global__ void fill_perm(const int* __restrict__ seg, int* __restrict__ cur, int* __restrict__ perm){
    int k = blockIdx.x*256 + threadIdx.x;
    if (k < NNZK){ int p = atomicAdd(&cur[seg[k]], 1); perm[p] = k; }
}

// ---------------------------------------------------------------- x -> bf16 stream
__global__ __launch_bounds__(256) void convert_x(const float4* __restrict__ x,
                                                 bf16x8* __restrict__ xb, int n8){
    int stride = gridDim.x*256;
    for (int i = blockIdx.x*256 + threadIdx.x; i < n8; i += stride){
        float4 lo = x[2*i], hi = x[2*i+1];
        bf16x8 v;
        v[0]=f2b(lo.x); v[1]=f2b(lo.y); v[2]=f2b(lo.z); v[3]=f2b(lo.w);
        v[4]=f2b(hi.x); v[5]=f2b(hi.y); v[6]=f2b(hi.z); v[7]=f2b(hi.w);
        xb[i] = v;
    }
}

// ------------------------------------------------ weight convert + transpose
__global__ void wconv_t(const float* __restrict__ W, __hip_bfloat16* __restrict__ BT, int K, int N){
    __shared__ float tile[32][33];
    int k0 = blockIdx.y*32, n0 = blockIdx.x*32;
    int tx = threadIdx.x & 31, ty = threadIdx.x >> 5;
    for (int i = ty; i < 32; i += 8) tile[i][tx] = W[(size_t)(k0+i)*N + n0+tx];
    __syncthreads();
    for (int i = ty; i < 32; i += 8)
        BT[(size_t)(n0+i)*K + k0 + tx] = __float2bfloat16(tile[tx][i]);
}

#define SWZ(b) ((b) ^ ((((b) >> 6) & 7) << 4))

// ---------------------------------------------------------------- all-bf16 GEMM (GEMM1)
// C_slice_z[M,N](bf16) = Ab[M,K] @ Bwt^T  (both bf16 K-major), split-K over blockIdx.z
__global__ __launch_bounds__(256) void gemm_bb(
    const __hip_bfloat16* __restrict__ Ab, const __hip_bfloat16* __restrict__ Bwt,
    __hip_bfloat16* __restrict__ Cb, int M, int N, int K, int kchunk)
{
    __shared__ f32x4 WsRaw[512];   // 8 KB
    __shared__ f32x4 XsRaw[512];   // 8 KB
    char* Ws = (char*)WsRaw;
    char* Xs = (char*)XsRaw;
    const int tid = threadIdx.x;
    const int lane = tid & 63;
    const int w = tid >> 6;
    const int m0 = blockIdx.y << 7, n0 = blockIdx.x << 7;
    const int kz = blockIdx.z * kchunk;
    const int wN = (w >> 1) << 6, wM = (w & 1) << 6;

    const int s0 = tid, s1 = tid + 256;
    const int r0 = s0 >> 2, k0b = (s0 & 3) << 3;
    const int r1 = s1 >> 2, k1b = (s1 & 3) << 3;
    const __hip_bfloat16* pA0 = Ab + (size_t)(m0 + r0)*K + kz + k0b;
    const __hip_bfloat16* pA1 = Ab + (size_t)(m0 + r1)*K + kz + k1b;
    const __hip_bfloat16* pW0 = Bwt + (size_t)(n0 + r0)*K + kz + k0b;
    const __hip_bfloat16* pW1 = Bwt + (size_t)(n0 + r1)*K + kz + k1b;
    const int wo0 = SWZ(s0 << 4), wo1 = SWZ(s1 << 4);

    int rwOff[4], rxOff[4];
#pragma unroll
    for (int f = 0; f < 4; f++){
        rwOff[f] = SWZ((wN + f*16 + (lane & 15))*64 + ((lane >> 4) << 4));
        rxOff[f] = SWZ((wM + f*16 + (lane & 15))*64 + ((lane >> 4) << 4));
    }

    f32x4 acc[4][4] = {};

    bf16x8 a0 = *(const bf16x8*)pA0, a1 = *(const bf16x8*)pA1;
    bf16x8 w0 = *(const bf16x8*)pW0, w1 = *(const bf16x8*)pW1;

    const int nsteps = kchunk >> 5;
    for (int ks = 0; ks < nsteps; ks++){
        __syncthreads();
        *(bf16x8*)(Xs + wo0) = a0;
        *(bf16x8*)(Xs + wo1) = a1;
        *(bf16x8*)(Ws + wo0) = w0;
        *(bf16x8*)(Ws + wo1) = w1;
        __syncthreads();
        if (ks + 1 < nsteps){
            pA0 += 32; pA1 += 32; pW0 += 32; pW1 += 32;
            a0 = *(const bf16x8*)pA0; a1 = *(const bf16x8*)pA1;
            w0 = *(const bf16x8*)pW0; w1 = *(const bf16x8*)pW1;
        }
        bf16x8 wf[4], xf[4];
#pragma unroll
        for (int f = 0; f < 4; f++){
            wf[f] = *(const bf16x8*)(Ws + rwOff[f]);
            xf[f] = *(const bf16x8*)(Xs + rxOff[f]);
        }
#pragma unroll
        for (int i = 0; i < 4; i++)
#pragma unroll
            for (int j = 0; j < 4; j++)
                acc[i][j] = __builtin_amdgcn_mfma_f32_16x16x32_bf16(wf[i], xf[j], acc[i][j], 0, 0, 0);
    }

    const int mc = wM + (lane & 15);
    const int ncb = wN + ((lane >> 4) << 2);
    __hip_bfloat16* Cz = Cb + (size_t)blockIdx.z * ((size_t)M * (size_t)N);
#pragma unroll
    for (int j = 0; j < 4; j++){
        int row = m0 + mc + j*16;
#pragma unroll
        for (int i = 0; i < 4; i++){
            int col = n0 + ncb + i*16;
            f32x4 v = acc[i][j];
            short4 sv = { f2b(v[0]), f2b(v[1]), f2b(v[2]), f2b(v[3]) };
            *(short4*)&Cz[(size_t)row*N + col] = sv;
        }
    }
}

// ---------------------------------------------------------------- MFMA GEMM (fp32 A, swapped orientation)
// MODE 0: plain fp32 store
// MODE 3: lrelu(acc + bias[col]) -> bf16 store
// MODE 5: plain bf16 store
template<int MODE>
__global__ __launch_bounds__(256) void gemm_nt(
    const float* __restrict__ Aact, const __hip_bfloat16* __restrict__ Bwt,
    float* __restrict__ C, __hip_bfloat16* __restrict__ Cb, const float* __restrict__ bias,
    int M, int N, int K, int kchunk)
{
    __shared__ f32x4 WsRaw[512];   // 8 KB
    __shared__ f32x4 XsRaw[512];   // 8 KB
    char* Ws = (char*)WsRaw;
    char* Xs = (char*)XsRaw;
    const int tid = threadIdx.x;
    const int lane = tid & 63;
    const int w = tid >> 6;
    const int m0 = blockIdx.y << 7, n0 = blockIdx.x << 7;
    const int wN = (w >> 1) << 6, wM = (w & 1) << 6;

    const int s0 = tid, s1 = tid + 256;
    const int r0 = s0 >> 2, k0b = (s0 & 3) << 3;
    const int r1 = s1 >> 2, k1b = (s1 & 3) << 3;
    const float* pX0 = Aact + (size_t)(m0 + r0)*K + k0b;
    const float* pX1 = Aact + (size_t)(m0 + r1)*K + k1b;
    const __hip_bfloat16* pW0 = Bwt + (size_t)(n0 + r0)*K + k0b;
    const __hip_bfloat16* pW1 = Bwt + (size_t)(n0 + r1)*K + k1b;
    const int wo0 = SWZ(s0 << 4), wo1 = SWZ(s1 << 4);

    int rwOff[4], rxOff[4];
#pragma unroll
    for (int f = 0; f < 4; f++){
        rwOff[f] = SWZ((wN + f*16 + (lane & 15))*64 + ((lane >> 4) << 4));
        rxOff[f] = SWZ((wM + f*16 + (lane & 15))*64 + ((lane >> 4) << 4));
    }

    f32x4 acc[4][4] = {};

    float4 x0l = *(const float4*)pX0, x0h = *(const float4*)(pX0+4);
    float4 x1l = *(const float4*)pX1, x1h = *(const float4*)(pX1+4);
    bf16x8 w0 = *(const bf16x8*)pW0, w1 = *(const bf16x8*)pW1;

    const int nsteps = kchunk >> 5;
    for (int ks = 0; ks < nsteps; ks++){
        bf16x8 vx0, vx1;
        vx0[0]=f2b(x0l.x); vx0[1]=f2b(x0l.y); vx0[2]=f2b(x0l.z); vx0[3]=f2b(x0l.w);
        vx0[4]=f2b(x0h.x); vx0[5]=f2b(x0h.y); vx0[6]=f2b(x0h.z); vx0[7]=f2b(x0h.w);
        vx1[0]=f2b(x1l.x); vx1[1]=f2b(x1l.y); vx1[2]=f2b(x1l.z); vx1[3]=f2b(x1l.w);
        vx1[4]=f2b(x1h.x); vx1[5]=f2b(x1h.y); vx1[6]=f2b(x1h.z); vx1[7]=f2b(x1h.w);
        __syncthreads();
        *(bf16x8*)(Xs + wo0) = vx0;
        *(bf16x8*)(Xs + wo1) = vx1;
        *(bf16x8*)(Ws + wo0) = w0;
        *(bf16x8*)(Ws + wo1) = w1;
        __syncthreads();
        if (ks + 1 < nsteps){
            pX0 += 32; pX1 += 32; pW0 += 32; pW1 += 32;
            x0l = *(const float4*)pX0; x0h = *(const float4*)(pX0+4);
            x1l = *(const float4*)pX1; x1h = *(const float4*)(pX1+4);
            w0 = *(const bf16x8*)pW0;  w1 = *(const bf16x8*)pW1;
        }
        bf16x8 wf[4], xf[4];
#pragma unroll
        for (int f = 0; f < 4; f++){
            wf[f] = *(const bf16x8*)(Ws + rwOff[f]);
            xf[f] = *(const bf16x8*)(Xs + rxOff[f]);
        }
#pragma unroll
        for (int i = 0; i < 4; i++)
#pragma unroll
            for (int j = 0; j < 4; j++)
                acc[i][j] = __builtin_amdgcn_mfma_f32_16x16x32_bf16(wf[i], xf[j], acc[i][j], 0, 0, 0);
    }

    const int mc = wM + (lane & 15);
    const int ncb = wN + ((lane >> 4) << 2);
#pragma unroll
    for (int j = 0; j < 4; j++){
        int row = m0 + mc + j*16;
#pragma unroll
        for (int i = 0; i < 4; i++){
            int col = n0 + ncb + i*16;
            f32x4 v = acc[i][j];
            if (MODE == 0){
                *(float4*)&C[(size_t)row*N + col] = *(float4*)&v;
            } else if (MODE == 5){
                short4 sv = { f2b(v[0]), f2b(v[1]), f2b(v[2]), f2b(v[3]) };
                *(short4*)&Cb[(size_t)row*N + col] = sv;
            } else {  // MODE 3
                float4 b4 = *(const float4*)&bias[col];
                short4 sv = { f2b(lrelu(v[0] + b4.x)), f2b(lrelu(v[1] + b4.y)),
                              f2b(lrelu(v[2] + b4.z)), f2b(lrelu(v[3] + b4.w)) };
                *(short4*)&Cb[(size_t)row*N + col] = sv;
            }
        }
    }
}

// split-K reduce (bf16 partials) + bias + lrelu + fused BN stats (row length 128 floats)
__global__ void reduce8s(const __hip_bfloat16* __restrict__ part, const float* __restrict__ bias,
                         float* __restrict__ out, int nf4, int parts, float* __restrict__ slots){
    int tid = threadIdx.x;
    int i = blockIdx.x*256 + tid;
    const short4* p4 = (const short4*)part;
    short4 v0 = p4[i];
    float4 s = { b2f(v0.x), b2f(v0.y), b2f(v0.z), b2f(v0.w) };
    for (int z = 1; z < parts; z++){
        short4 p = p4[(size_t)z*nf4 + i];
        s.x += b2f(p.x); s.y += b2f(p.y); s.z += b2f(p.z); s.w += b2f(p.w);
    }
    int c0 = (i & 31) << 2;
    s.x = lrelu(s.x + bias[c0+0]); s.y = lrelu(s.y + bias[c0+1]);
    s.z = lrelu(s.z + bias[c0+2]); s.w = lrelu(s.w + bias[c0+3]);
    ((float4*)out)[i] = s;
    __shared__ float S[128], Q[128];
    if (tid < 128){ S[tid] = 0.f; Q[tid] = 0.f; }
    __syncthreads();
    atomicAdd(&S[c0+0], s.x); atomicAdd(&Q[c0+0], s.x*s.x);
    atomicAdd(&S[c0+1], s.y); atomicAdd(&Q[c0+1], s.y*s.y);
    atomicAdd(&S[c0+2], s.z); atomicAdd(&Q[c0+2], s.z*s.z);
    atomicAdd(&S[c0+3], s.w); atomicAdd(&Q[c0+3], s.w*s.w);
    __syncthreads();
    if (tid < 128){
        int slot = blockIdx.x & 31;
        atomicAdd(&slots[slot*256 + tid], S[tid]);
        atomicAdd(&slots[slot*256 + 128 + tid], Q[tid]);
    }
}

// ---------------------------------------------------------------- final stage streaming (all bf16 reads)
__global__ __launch_bounds__(256) void final_stats(
    const bf16x8* __restrict__ xb, const bf16x8* __restrict__ f,
    float* __restrict__ slots, int n8)
{
    int tid = threadIdx.x;
    float s[8] = {0,0,0,0,0,0,0,0}, q[8] = {0,0,0,0,0,0,0,0};
    int stride = gridDim.x*256;
    for (int i = blockIdx.x*256 + tid; i < n8; i += stride){
        bf16x8 xv = xb[i], fv = f[i];
#pragma unroll
        for (int j = 0; j < 8; j++){
            float y = b2f(xv[j]) + b2f(fv[j]);
            s[j] += y; q[j] += y*y;
        }
    }
    __shared__ float S[128], Q[128];
    if (tid < 128){ S[tid] = 0.f; Q[tid] = 0.f; }
    __syncthreads();
    int c0 = (tid & 15) << 3;
#pragma unroll
    for (int j = 0; j < 8; j++){
        atomicAdd(&S[c0+j], s[j]);
        atomicAdd(&Q[c0+j], q[j]);
    }
    __syncthreads();
    if (tid < 128){
        int slot = blockIdx.x & 31;
        atomicAdd(&slots[slot*256 + tid], S[tid]);
        atomicAdd(&slots[slot*256 + 128 + tid], Q[tid]);
    }
}

__global__ __launch_bounds__(256) void final_apply(
    const bf16x8* __restrict__ xb, const bf16x8* __restrict__ f,
    const float* __restrict__ coef, float4* __restrict__ out, int n8)
{
    int tid = threadIdx.x;
    int c0 = (tid & 15) << 3;
    float sc[8], sh[8];
#pragma unroll
    for (int j = 0; j < 8; j++){ sc[j] = coef[c0+j]; sh[j] = coef[128+c0+j]; }
    int stride = gridDim.x*256;
    for (int i = blockIdx.x*256 + tid; i < n8; i += stride){
        bf16x8 xv = xb[i], fv = f[i];
        float4 lo, hi;
        lo.x = (b2f(xv[0]) + b2f(fv[0]))*sc[0] + sh[0];
        lo.y = (b2f(xv[1]) + b2f(fv[1]))*sc[1] + sh[1];
        lo.z = (b2f(xv[2]) + b2f(fv[2]))*sc[2] + sh[2];
        lo.w = (b2f(xv[3]) + b2f(fv[3]))*sc[3] + sh[3];
        hi.x = (b2f(xv[4]) + b2f(fv[4]))*sc[4] + sh[4];
        hi.y = (b2f(xv[5]) + b2f(fv[5]))*sc[5] + sh[5];
        hi.z = (b2f(xv[6]) + b2f(fv[6]))*sc[6] + sh[6];
        hi.w = (b2f(xv[7]) + b2f(fv[7]))*sc[7] + sh[7];
        out[2*i]   = lo;
        out[2*i+1] = hi;
    }
}

// ---------------------------------------------------------------- BatchNorm
__global__ void bn_stats_v2(const float* __restrict__ x, float* __restrict__ slots, int rows){
    int cg = threadIdx.x & 31, rg = threadIdx.x >> 5;
    float4 s = {0,0,0,0}, q = {0,0,0,0};
    for (int r = blockIdx.x*8 + rg; r < rows; r += gridDim.x*8){
        float4 v = ((const float4*)x)[(size_t)r*32 + cg];
        s.x += v.x; q.x += v.x*v.x;
        s.y += v.y; q.y += v.y*v.y;
        s.z += v.z; q.z += v.z*v.z;
        s.w += v.w; q.w += v.w*v.w;
    }
    __shared__ float S[128], Q[128];
    if (threadIdx.x < 128){ S[threadIdx.x] = 0.f; Q[threadIdx.x] = 0.f; }
    __syncthreads();
    int c0 = cg << 2;
    atomicAdd(&S[c0+0], s.x); atomicAdd(&Q[c0+0], q.x);
    atomicAdd(&S[c0+1], s.y); atomicAdd(&Q[c0+1], q.y);
    atomicAdd(&S[c0+2], s.z); atomicAdd(&Q[c0+2], q.z);
    atomicAdd(&S[c0+3], s.w); atomicAdd(&Q[c0+3], q.w);
    __syncthreads();
    if (threadIdx.x < 128){
        int slot = blockIdx.x & 31;
        atomicAdd(&slots[slot*256 + threadIdx.x], S[threadIdx.x]);
        atomicAdd(&slots[slot*256 + 128 + threadIdx.x], Q[threadIdx.x]);
    }
}

__global__ void bn_finalize2(const float* __restrict__ slots, int nslots,
                             const float* __restrict__ g, const float* __restrict__ b,
                             float invR, float* __restrict__ coef){
    int c = threadIdx.x;
    float s = 0.f, q = 0.f;
    for (int k = 0; k < nslots; k++){ s += slots[k*256 + c]; q += slots[k*256 + 128 + c]; }
    float m = s*invR;
    float v = q*invR - m*m;
    float sc = g[c]*rsqrtf(v + EPSV);
    coef[c] = sc;
    coef[128 + c] = b[c] - m*sc;
}

__global__ void bn_apply4(float4* __restrict__ x, const float* __restrict__ coef, size_t n4){
    size_t i = (size_t)blockIdx.x*blockDim.x + threadIdx.x;
    size_t stride = (size_t)gridDim.x*blockDim.x;
    for (; i < n4; i += stride){
        int c0 = (int)(i & 31) * 4;
        float4 v = x[i];
        v.x = v.x*coef[c0+0] + coef[128+c0+0];
        v.y = v.y*coef[c0+1] + coef[128+c0+1];
        v.z = v.z*coef[c0+2] + coef[128+c0+2];
        v.w = v.w*coef[c0+3] + coef[128+c0+3];
        x[i] = v;
    }
}

// ---------------------------------------------------------------- segment ops
__global__ void seg_sum_edge(const int* __restrict__ eoff, const int* __restrict__ eperm,
                             const int* __restrict__ he_n, const float* __restrict__ h,
                             float* __restrict__ out){
    int m = blockIdx.x, c = threadIdx.x;
    int s0 = eoff[m], cnt = eoff[m+1] - s0;
    __shared__ int sn[128];
    float acc = 0.f;
    for (int base = 0; base < cnt; base += 128){
        int i = base + c;
        if (i < cnt) sn[c] = he_n[eperm[s0+i]];
        __syncthreads();
        int lim = min(128, cnt - base);
        for (int j = 0; j < lim; j++) acc += h[(size_t)sn[j]*128 + c];
        __syncthreads();
    }
    out[(size_t)m*128 + c] = acc;
}

// heads=4, bf16 features
__global__ void row_att4b(const __hip_bfloat16* __restrict__ xt, const float* __restrict__ att,
                          int aoff, float* __restrict__ out){
    int n = blockIdx.x, lane = threadIdx.x;  // 64
#pragma unroll
    for (int h = 0; h < 4; h++){
        const __hip_bfloat16* xr = xt + (size_t)n*512 + h*128;
        const float* ar = att + h*256 + aoff;
        float s = b2f(((const short*)xr)[2*lane])*ar[2*lane]
                + b2f(((const short*)xr)[2*lane+1])*ar[2*lane+1];
        for (int d = 32; d > 0; d >>= 1) s += __shfl_down(s, d);
        if (lane == 0) out[n*4 + h] = s;
    }
}

template<int H>
__global__ void row_att(const float* __restrict__ xt, const float* __restrict__ att,
                        int aoff, float* __restrict__ out){
    int n = blockIdx.x, lane = threadIdx.x;
#pragma unroll
    for (int h = 0; h < H; h++){
        const float* xr = xt + (size_t)n*(H*128) + h*128;
        const float* ar = att + h*256 + aoff;
        float s = xr[lane]*ar[lane] + xr[lane+64]*ar[lane+64];
        for (int d = 32; d > 0; d >>= 1) s += __shfl_down(s, d);
        if (lane == 0) out[n*H + h] = s;
    }
}

template<int H>
__global__ void seg_softmax(const int* __restrict__ eoff, const int* __restrict__ eperm,
                            const int* __restrict__ he_n,
                            const float* __restrict__ ax, const float* __restrict__ ae,
                            float* __restrict__ alpha){
    int m = blockIdx.x, t = threadIdx.x;
    int s0 = eoff[m], cnt = eoff[m+1] - s0;
    if (cnt == 0) return;
    __shared__ float red[128];
    float aeh[H];
#pragma unroll
    for (int h = 0; h < H; h++) aeh[h] = ae[m*H + h];
    float lmax[H];
#pragma unroll
    for (int h = 0; h < H; h++) lmax[h] = -1e30f;
    for (int i = t; i < cnt; i += 128){
        int k = eperm[s0+i]; int n = he_n[k];
#pragma unroll
        for (int h = 0; h < H; h++){
            float v = lrelu(ax[n*H + h] + aeh[h]);
            alpha[(size_t)k*H + h] = v;
            lmax[h] = fmaxf(lmax[h], v);
        }
    }
    float gmax[H];
#pragma unroll
    for (int h = 0; h < H; h++){
        red[t] = lmax[h]; __syncthreads();
        for (int s = 64; s > 0; s >>= 1){ if (t < s) red[t] = fmaxf(red[t], red[t+s]); __syncthreads(); }
        gmax[h] = red[0]; __syncthreads();
    }
    float lsum[H];
#pragma unroll
    for (int h = 0; h < H; h++) lsum[h] = 0.f;
    for (int i = t; i < cnt; i += 128){
        int k = eperm[s0+i];
#pragma unroll
        for (int h = 0; h < H; h++){
            float ex = __expf(alpha[(size_t)k*H + h] - gmax[h]);
            alpha[(size_t)k*H + h] = ex;
            lsum[h] += ex;
        }
    }
    float ginv[H];
#pragma unroll
    for (int h = 0; h < H; h++){
        red[t] = lsum[h]; __syncthreads();
        for (int s = 64; s > 0; s >>= 1){ if (t < s) red[t] += red[t+s]; __syncthreads(); }
        ginv[h] = 1.f/red[0]; __syncthreads();
    }
    for (int i = t; i < cnt; i += 128){
        int k = eperm[s0+i];
#pragma unroll
        for (int h = 0; h < H; h++) alpha[(size_t)k*H + h] *= ginv[h];
    }
}

// heads=4, bf16 xt
__global__ void seg_eo4(const int* __restrict__ eoff, const int* __restrict__ eperm,
                        const int* __restrict__ he_n,
                        const float* __restrict__ alpha, const __hip_bfloat16* __restrict__ xt,
                        float* __restrict__ eo){
    int m = blockIdx.x;
    int c = threadIdx.x & 127, hb = threadIdx.x >> 7;   // hb in {0,1}
    int s0 = eoff[m], cnt = eoff[m+1] - s0;
    __shared__ int sn[128];
    __shared__ float sa[128][4];
    float acc0 = 0.f, acc1 = 0.f;
    for (int base = 0; base < cnt; base += 128){
        int i = base + threadIdx.x;
        if (threadIdx.x < 128 && i < cnt){
            int k = eperm[s0+i];
            sn[threadIdx.x] = he_n[k];
#pragma unroll
            for (int h = 0; h < 4; h++) sa[threadIdx.x][h] = alpha[(size_t)k*4 + h];
        }
        __syncthreads();
        int lim = min(128, cnt - base);
        for (int j = 0; j < lim; j++){
            const short* xr = (const short*)(xt + (size_t)sn[j]*512);
            acc0 += sa[j][hb]   * b2f(xr[hb*128 + c]);
            acc1 += sa[j][hb+2] * b2f(xr[(hb+2)*128 + c]);
        }
        __syncthreads();
    }
    float binv = cnt > 0 ? 1.f/(float)cnt : 0.f;
    eo[(size_t)m*512 + hb*128 + c]     = acc0*binv;
    eo[(size_t)m*512 + (hb+2)*128 + c] = acc1*binv;
}

__global__ void seg_eo1(const int* __restrict__ eoff, const int* __restrict__ eperm,
                        const int* __restrict__ he_n,
                        const float* __restrict__ alpha, const float* __restrict__ xt,
                        float* __restrict__ eo){
    int m = blockIdx.x, c = threadIdx.x;
    int s0 = eoff[m], cnt = eoff[m+1] - s0;
    __shared__ int sn[128];
    __shared__ float sa[128];
    float acc = 0.f;
    for (int base = 0; base < cnt; base += 128){
        int i = base + c;
        if (i < cnt){
            int k = eperm[s0+i];
            sn[c] = he_n[k];
            sa[c] = alpha[k];
        }
        __syncthreads();
        int lim = min(128, cnt - base);
        for (int j = 0; j < lim; j++) acc += sa[j]*xt[(size_t)sn[j]*128 + c];
        __syncthreads();
    }
    float binv = cnt > 0 ? 1.f/(float)cnt : 0.f;
    eo[(size_t)m*128 + c] = acc*binv;
}

template<int H>
__global__ void seg_node_out(const int* __restrict__ noff, const int* __restrict__ nperm,
                             const int* __restrict__ he_e,
                             const float* __restrict__ alpha, const float* __restrict__ eo,
                             const float* __restrict__ hin, const float* __restrict__ bias,
                             float* __restrict__ hout){
    int n = blockIdx.x, c = threadIdx.x;
    int s0 = noff[n], cnt = noff[n+1] - s0;
    float acc = 0.f;
    for (int i = 0; i < cnt; i++){
        int k = nperm[s0+i]; int e = he_e[k];
        const float* er = eo + (size_t)e*(128*H);
#pragma unroll
        for (int h = 0; h < H; h++) acc += alpha[(size_t)k*H + h]*er[h*128 + c];
    }
    float dinv = cnt > 0 ? 1.f/((float)cnt*(float)H) : 0.f;
    hout[(size_t)n*128 + c] = hin[(size_t)n*128 + c] + bias[c] + acc*dinv;
}

// ---------------------------------------------------------------- launcher
extern "C" void kernel_launch(void* const* d_in, const int* in_sizes, int n_in,
                              void* d_out, int out_size, void* d_ws, size_t ws_size,
                              hipStream_t stream){
    const float* x    = (const float*)d_in[0];
    const int*   he_n = (const int*)  d_in[1];
    const int*   he_e = (const int*)  d_in[2];
    const float* W1   = (const float*)d_in[3];
    const float* b1   = (const float*)d_in[4];
    const float* g1   = (const float*)d_in[5];
    const float* be1  = (const float*)d_in[6];
    const float* Wh1  = (const float*)d_in[7];
    const float* att1 = (const float*)d_in[8];
    const float* bh1  = (const float*)d_in[9];
    const float* g2   = (const float*)d_in[10];
    const float* be2  = (const float*)d_in[11];
    const float* Wh2  = (const float*)d_in[12];
    const float* att2 = (const float*)d_in[13];
    const float* bh2  = (const float*)d_in[14];
    const float* g3   = (const float*)d_in[15];
    const float* be3  = (const float*)d_in[16];
    const float* W3   = (const float*)d_in[17];
    const float* b3   = (const float*)d_in[18];
    const float* g4   = (const float*)d_in[19];
    const float* be4  = (const float*)d_in[20];
    float* out = (float*)d_out;

    char* ws = (char*)d_ws;
    size_t off = 0;
    auto alloc = [&](size_t bytes)->char*{ char* p = ws + off; off += (bytes + 255) & ~(size_t)255; return p; };

    // big region (64 MB): fbuf (final stage) aliases part (GEMM1 stage) + xt1 (hconv1 stage)
    char* big = alloc((size_t)NN*DIN*2);
    __hip_bfloat16* fbuf = (__hip_bfloat16*)big;
    __hip_bfloat16* part = (__hip_bfloat16*)big;                       // 16 slices x 2MB = 32MB
    __hip_bfloat16* xt1b = (__hip_bfloat16*)(big + (size_t)16*NN*128*2); // 9.4MB at +32MB
    __hip_bfloat16* xbuf = (__hip_bfloat16*)alloc((size_t)NN*DIN*2);   // bf16 copy of x (64MB)

    float* hall1  = (float*)alloc((size_t)MALL*128*4);
    float* hall2  = (float*)alloc((size_t)MALL*128*4);
    float* h3     = (float*)alloc((size_t)NN*128*4);
    float* xt2    = (float*)alloc((size_t)MALL*128*4);
    float* eo     = (float*)alloc((size_t)MME*512*4);
    float* alpha  = (float*)alloc((size_t)NNZK*4*4);
    float* ax     = (float*)alloc((size_t)NN*4*4);
    float* ae     = (float*)alloc((size_t)MME*4*4);
    float* slots  = (float*)alloc((size_t)32*256*4);
    float* coef   = (float*)alloc(256*4);
    __hip_bfloat16* W1T  = (__hip_bfloat16*)alloc((size_t)128*DIN*2);
    __hip_bfloat16* Wh1T = (__hip_bfloat16*)alloc((size_t)512*128*2);
    __hip_bfloat16* Wh2T = (__hip_bfloat16*)alloc((size_t)128*128*2);
    __hip_bfloat16* W3T  = (__hip_bfloat16*)alloc((size_t)DIN*128*2);
    int* ecnt  = (int*)alloc(MME*4);
    int* ncnt  = (int*)alloc(NN*4);
    int* eoffb = (int*)alloc((MME+1)*4);
    int* ecur  = (int*)alloc(MME*4);
    int* noffb = (int*)alloc((NN+1)*4);
    int* ncur  = (int*)alloc(NN*4);
    int* eperm = (int*)alloc((size_t)NNZK*4);
    int* nperm = (int*)alloc((size_t)NNZK*4);

    // ---- x -> bf16 (single full-rate stream pass; reused by GEMM1 and final stage) ----
    convert_x<<<2048, 256, 0, stream>>>((const float4*)x, (bf16x8*)xbuf, NN*DIN/8);

    // ---- CSR build ----
    zero_i<<<(MME+NN+255)/256, 256, 0, stream>>>(ecnt, MME+NN);   // ecnt+ncnt adjacent
    count_seg<<<NNZK/256, 256, 0, stream>>>(he_n, he_e, ncnt, ecnt);
    scan_excl<<<1, 1024, 0, stream>>>(ecnt, eoffb, MME);
    scan_excl<<<1, 1024, 0, stream>>>(ncnt, noffb, NN);
    copy_i<<<(MME+255)/256, 256, 0, stream>>>(eoffb, ecur, MME);
    copy_i<<<(NN+255)/256, 256, 0, stream>>>(noffb, ncur, NN);
    fill_perm<<<NNZK/256, 256, 0, stream>>>(he_e, ecur, eperm);
    fill_perm<<<NNZK/256, 256, 0, stream>>>(he_n, ncur, nperm);

    // ---- weight transpose+convert ----
    wconv_t<<<dim3(128/32, DIN/32), 256, 0, stream>>>(W1,  W1T,  DIN, 128);
    wconv_t<<<dim3(512/32, 128/32), 256, 0, stream>>>(Wh1, Wh1T, 128, 512);
    wconv_t<<<dim3(128/32, 128/32), 256, 0, stream>>>(Wh2, Wh2T, 128, 128);
    wconv_t<<<dim3(DIN/32, 128/32), 256, 0, stream>>>(W3,  W3T,  128, DIN);

    // ---- layer 0: h1 = lrelu(xb @ W1 + b1); BN1 (stats fused in reduce8s) ----
    gemm_bb<<<dim3(1, NN/128, 16), 256, 0, stream>>>(xbuf, W1T, part, NN, 128, DIN, DIN/16);
    zero_f<<<32, 256, 0, stream>>>(slots, 32*256);
    reduce8s<<<NN*128/4/256, 256, 0, stream>>>(part, b1, hall1, NN*128/4, 16, slots);
    bn_finalize2<<<1, 128, 0, stream>>>(slots, 32, g1, be1, 1.f/NN, coef);
    bn_apply4<<<1024, 256, 0, stream>>>((float4*)hall1, coef, (size_t)NN*32);

    // ---- hconv1 (heads=4) ----
    seg_sum_edge<<<MME, 128, 0, stream>>>(eoffb, eperm, he_n, hall1, hall1 + (size_t)NN*128);
    gemm_nt<5><<<dim3(512/128, MALL/128, 1), 256, 0, stream>>>(hall1, Wh1T, nullptr, xt1b, nullptr, MALL, 512, 128, 128);
    row_att4b<<<NN, 64, 0, stream>>>(xt1b, att1, 0, ax);
    row_att4b<<<MME, 64, 0, stream>>>(xt1b + (size_t)NN*512, att1, 128, ae);
    seg_softmax<4><<<MME, 128, 0, stream>>>(eoffb, eperm, he_n, ax, ae, alpha);
    seg_eo4<<<MME, 256, 0, stream>>>(eoffb, eperm, he_n, alpha, xt1b, eo);
    seg_node_out<4><<<NN, 128, 0, stream>>>(noffb, nperm, he_e, alpha, eo, hall1, bh1, hall2);
    zero_f<<<32, 256, 0, stream>>>(slots, 32*256);
    bn_stats_v2<<<256, 256, 0, stream>>>(hall2, slots, NN);
    bn_finalize2<<<1, 128, 0, stream>>>(slots, 32, g2, be2, 1.f/NN, coef);
    bn_apply4<<<1024, 256, 0, stream>>>((float4*)hall2, coef, (size_t)NN*32);

    // ---- hconv2 (heads=1) ----
    seg_sum_edge<<<MME, 128, 0, stream>>>(eoffb, eperm, he_n, hall2, hall2 + (size_t)NN*128);
    gemm_nt<0><<<dim3(1, MALL/128, 1), 256, 0, stream>>>(hall2, Wh2T, xt2, nullptr, nullptr, MALL, 128, 128, 128);
    row_att<1><<<NN, 64, 0, stream>>>(xt2, att2, 0, ax);
    row_att<1><<<MME, 64, 0, stream>>>(xt2 + (size_t)NN*128, att2, 128, ae);
    seg_softmax<1><<<MME, 128, 0, stream>>>(eoffb, eperm, he_n, ax, ae, alpha);
    seg_eo1<<<MME, 128, 0, stream>>>(eoffb, eperm, he_n, alpha, xt2, eo);
    seg_node_out<1><<<NN, 128, 0, stream>>>(noffb, nperm, he_e, alpha, eo, hall2, bh2, h3);
    zero_f<<<32, 256, 0, stream>>>(slots, 32*256);
    bn_stats_v2<<<256, 256, 0, stream>>>(h3, slots, NN);
    bn_finalize2<<<1, 128, 0, stream>>>(slots, 32, g3, be3, 1.f/NN, coef);
    bn_apply4<<<1024, 256, 0, stream>>>((float4*)h3, coef, (size_t)NN*32);

    // ---- final: out = BN4(x + lrelu(h3 @ W3 + b3)) ----
    gemm_nt<3><<<dim3(DIN/128, NN/128, 1), 256, 0, stream>>>(h3, W3T, nullptr, fbuf, b3, NN, DIN, 128, 128);
    zero_f<<<32, 256, 0, stream>>>(slots, 32*256);
    final_stats<<<2048, 256, 0, stream>>>((const bf16x8*)xbuf, (const bf16x8*)fbuf, slots, NN*DIN/8);
    bn_finalize2<<<1, 128, 0, stream>>>(slots, 32, g4, be4, 1.f/((float)NN*TT), coef);
    final_apply<<<2048, 256, 0, stream>>>((const bf16x8*)xbuf, (const bf16x8*)fbuf, coef, (float4*)out, NN*DIN/8);
}

// Round 8
// 550.371 us; speedup vs baseline: 1.0441x; 1.0116x over previous
//
#include <hip/hip_runtime.h>
#include <hip/hip_bf16.h>
#include <math.h>

#define NN   8192
#define TT   32
#define DIN  4096
#define MME  1024
#define NNZK 131072
#define EPSV 1e-5f
#define MALL (NN + MME)   // 9216 combined node+edge rows
#define NSLOT 8

typedef __attribute__((ext_vector_type(8))) short bf16x8;
typedef __attribute__((ext_vector_type(4))) float f32x4;

__device__ __forceinline__ float lrelu(float v){ return v > 0.f ? v : 0.2f*v; }
__device__ __forceinline__ short f2b(float f){
    union { __hip_bfloat16 h; short s; } u; u.h = __float2bfloat16(f); return u.s;
}
__device__ __forceinline__ float b2f(short s){
    union { float f; unsigned u; } u; u.u = ((unsigned)(unsigned short)s) << 16; return u.f;
}

// ---------------------------------------------------------------- utilities
__global__ void zero_i(int* p, int n){ int i = blockIdx.x*256 + threadIdx.x; if (i < n) p[i] = 0; }
__global__ void zero_f(float* p, int n){ int i = blockIdx.x*256 + threadIdx.x; if (i < n) p[i] = 0.f; }

__global__ void count_seg(const int* __restrict__ he_n, const int* __restrict__ he_e,
                          int* __restrict__ ncnt, int* __restrict__ ecnt){
    int k = blockIdx.x*256 + threadIdx.x;
    if (k < NNZK){ atomicAdd(&ecnt[he_e[k]], 1); atomicAdd(&ncnt[he_n[k]], 1); }
}

// single-block exclusive scan, wave-shuffle based (n multiple of 1024); writes off AND cur
__global__ void scan_excl(const int* __restrict__ cnt, int* __restrict__ off,
                          int* __restrict__ cur, int n){
    int t = threadIdx.x;              // 1024 threads
    int lane = t & 63, wv = t >> 6;   // 16 waves
    int chunk = n >> 10;
    int base = t*chunk;
    int s = 0;
#pragma unroll 4
    for (int i = 0; i < chunk; i++) s += cnt[base+i];
    int v = s;
    for (int d = 1; d < 64; d <<= 1){
        int u = __shfl_up(v, d);
        if (lane >= d) v += u;
    }
    __shared__ int wsum[16];
    if (lane == 63) wsum[wv] = v;
    __syncthreads();
    if (wv == 0 && lane < 16){
        int w2 = wsum[lane];
        for (int d = 1; d < 16; d <<= 1){
            int u = __shfl_up(w2, d);
            if (lane >= d) w2 += u;
        }
        wsum[lane] = w2;
    }
    __syncthreads();
    int excl = v - s + (wv > 0 ? wsum[wv-1] : 0);
    for (int i = 0; i < chunk; i++){
        off[base+i] = excl;
        cur[base+i] = excl;
        excl += cnt[base+i];
    }
    if (t == 1023) off[n] = excl;
}

// perm fill that also materializes the sorted "other endpoint" array
__global__ void fill_perm2(const int* __restrict__ seg, const int* __restrict__ other,
                           int* __restrict__ cur, int* __restrict__ perm, int* __restrict__ oth){
    int k = blockIdx.x*256 + threadIdx.x;
    if (k < NNZK){
        int p = atomicAdd(&cur[seg[k]], 1);
        perm[p] = k;
        oth[p] = other[k];
    }
}

// ------------------------------------------------ weight convert + transpose
__global__ void wconv_t(const float* __restrict__ W, __hip_bfloat16* __restrict__ BT, int K, int N){
    __shared__ float tile[32][33];
    int k0 = blockIdx.y*32, n0 = blockIdx.x*32;
    int tx = threadIdx.x & 31, ty = threadIdx.x >> 5;
    for (int i = ty; i < 32; i += 8) tile[i][tx] = W[(size_t)(k0+i)*N + n0+tx];
    __syncthreads();
    for (int i = ty; i < 32; i += 8)
        BT[(size_t)(n0+i)*K + k0 + tx] = __float2bfloat16(tile[tx][i]);
}

#define SWZ(b) ((b) ^ ((((b) >> 6) & 7) << 4))

// ---------------------------------------------------------------- MFMA GEMM (fp32 A, swapped orientation)
// C[M,N] = Aact[M,K] @ Bwt^T, Bwt is [N,K] bf16. Lane's f32x4 acc = 4 consecutive cols.
// MODE 0: fp32 store
// MODE 2: bf16 store to split-K slice blockIdx.z
// MODE 5: bf16 store
// MODE 6: y = lrelu(acc+bias)+xadd; bf16 store; fused per-channel sum/sumsq -> slots
template<int MODE>
__global__ __launch_bounds__(256) void gemm_nt(
    const float* __restrict__ Aact, const __hip_bfloat16* __restrict__ Bwt,
    float* __restrict__ C, __hip_bfloat16* __restrict__ Cb, const float* __restrict__ bias,
    const float* __restrict__ xadd, float* __restrict__ slots,
    int M, int N, int K, int kchunk)
{
    __shared__ f32x4 WsRaw[512];   // 8 KB
    __shared__ f32x4 XsRaw[512];   // 8 KB
    char* Ws = (char*)WsRaw;
    char* Xs = (char*)XsRaw;
    const int tid = threadIdx.x;
    const int lane = tid & 63;
    const int w = tid >> 6;
    const int m0 = blockIdx.y << 7, n0 = blockIdx.x << 7;
    const int kz = blockIdx.z * kchunk;
    const int wN = (w >> 1) << 6, wM = (w & 1) << 6;

    const int s0 = tid, s1 = tid + 256;
    const int r0 = s0 >> 2, k0b = (s0 & 3) << 3;
    const int r1 = s1 >> 2, k1b = (s1 & 3) << 3;
    const float* pX0 = Aact + (size_t)(m0 + r0)*K + kz + k0b;
    const float* pX1 = Aact + (size_t)(m0 + r1)*K + kz + k1b;
    const __hip_bfloat16* pW0 = Bwt + (size_t)(n0 + r0)*K + kz + k0b;
    const __hip_bfloat16* pW1 = Bwt + (size_t)(n0 + r1)*K + kz + k1b;
    const int wo0 = SWZ(s0 << 4), wo1 = SWZ(s1 << 4);

    int rwOff[4], rxOff[4];
#pragma unroll
    for (int f = 0; f < 4; f++){
        rwOff[f] = SWZ((wN + f*16 + (lane & 15))*64 + ((lane >> 4) << 4));
        rxOff[f] = SWZ((wM + f*16 + (lane & 15))*64 + ((lane >> 4) << 4));
    }

    f32x4 acc[4][4] = {};

    float4 x0l = *(const float4*)pX0, x0h = *(const float4*)(pX0+4);
    float4 x1l = *(const float4*)pX1, x1h = *(const float4*)(pX1+4);
    bf16x8 w0 = *(const bf16x8*)pW0, w1 = *(const bf16x8*)pW1;

    const int nsteps = kchunk >> 5;
    for (int ks = 0; ks < nsteps; ks++){
        bf16x8 vx0, vx1;
        vx0[0]=f2b(x0l.x); vx0[1]=f2b(x0l.y); vx0[2]=f2b(x0l.z); vx0[3]=f2b(x0l.w);
        vx0[4]=f2b(x0h.x); vx0[5]=f2b(x0h.y); vx0[6]=f2b(x0h.z); vx0[7]=f2b(x0h.w);
        vx1[0]=f2b(x1l.x); vx1[1]=f2b(x1l.y); vx1[2]=f2b(x1l.z); vx1[3]=f2b(x1l.w);
        vx1[4]=f2b(x1h.x); vx1[5]=f2b(x1h.y); vx1[6]=f2b(x1h.z); vx1[7]=f2b(x1h.w);
        __syncthreads();
        *(bf16x8*)(Xs + wo0) = vx0;
        *(bf16x8*)(Xs + wo1) = vx1;
        *(bf16x8*)(Ws + wo0) = w0;
        *(bf16x8*)(Ws + wo1) = w1;
        __syncthreads();
        if (ks + 1 < nsteps){
            pX0 += 32; pX1 += 32; pW0 += 32; pW1 += 32;
            x0l = *(const float4*)pX0; x0h = *(const float4*)(pX0+4);
            x1l = *(const float4*)pX1; x1h = *(const float4*)(pX1+4);
            w0 = *(const bf16x8*)pW0;  w1 = *(const bf16x8*)pW1;
        }
        bf16x8 wf[4], xf[4];
#pragma unroll
        for (int f = 0; f < 4; f++){
            wf[f] = *(const bf16x8*)(Ws + rwOff[f]);
            xf[f] = *(const bf16x8*)(Xs + rxOff[f]);
        }
#pragma unroll
        for (int i = 0; i < 4; i++)
#pragma unroll
            for (int j = 0; j < 4; j++)
                acc[i][j] = __builtin_amdgcn_mfma_f32_16x16x32_bf16(wf[i], xf[j], acc[i][j], 0, 0, 0);
    }

    const int mc = wM + (lane & 15);
    const int ncb = wN + ((lane >> 4) << 2);
    if (MODE == 6){
        __shared__ float sS[128], sQ[128];
        if (tid < 128){ sS[tid] = 0.f; sQ[tid] = 0.f; }
        __syncthreads();
        f32x4 s[4] = {}, q[4] = {};
#pragma unroll
        for (int j = 0; j < 4; j++){
            int row = m0 + mc + j*16;
#pragma unroll
            for (int i = 0; i < 4; i++){
                int col = n0 + ncb + i*16;
                f32x4 v = acc[i][j];
                float4 b4 = *(const float4*)&bias[col];
                float4 x4 = *(const float4*)&xadd[(size_t)row*N + col];
                float y0 = lrelu(v[0] + b4.x) + x4.x;
                float y1 = lrelu(v[1] + b4.y) + x4.y;
                float y2 = lrelu(v[2] + b4.z) + x4.z;
                float y3 = lrelu(v[3] + b4.w) + x4.w;
                short4 sv = { f2b(y0), f2b(y1), f2b(y2), f2b(y3) };
                *(short4*)&Cb[(size_t)row*N + col] = sv;
                s[i][0] += y0; q[i][0] += y0*y0;
                s[i][1] += y1; q[i][1] += y1*y1;
                s[i][2] += y2; q[i][2] += y2*y2;
                s[i][3] += y3; q[i][3] += y3*y3;
            }
        }
#pragma unroll
        for (int i = 0; i < 4; i++){
            int ch = (ncb + i*16) & 127;
            atomicAdd(&sS[ch+0], s[i][0]); atomicAdd(&sQ[ch+0], q[i][0]);
            atomicAdd(&sS[ch+1], s[i][1]); atomicAdd(&sQ[ch+1], q[i][1]);
            atomicAdd(&sS[ch+2], s[i][2]); atomicAdd(&sQ[ch+2], q[i][2]);
            atomicAdd(&sS[ch+3], s[i][3]); atomicAdd(&sQ[ch+3], q[i][3]);
        }
        __syncthreads();
        if (tid < 128){
            int slot = blockIdx.x & (NSLOT-1);
            atomicAdd(&slots[slot*256 + tid], sS[tid]);
            atomicAdd(&slots[slot*256 + 128 + tid], sQ[tid]);
        }
        return;
    }
#pragma unroll
    for (int j = 0; j < 4; j++){
        int row = m0 + mc + j*16;
#pragma unroll
        for (int i = 0; i < 4; i++){
            int col = n0 + ncb + i*16;
            f32x4 v = acc[i][j];
            if (MODE == 0){
                *(float4*)&C[(size_t)row*N + col] = *(float4*)&v;
            } else if (MODE == 2){
                __hip_bfloat16* Cz = Cb + (size_t)blockIdx.z * ((size_t)M * (size_t)N);
                short4 sv = { f2b(v[0]), f2b(v[1]), f2b(v[2]), f2b(v[3]) };
                *(short4*)&Cz[(size_t)row*N + col] = sv;
            } else {  // MODE 5
                short4 sv = { f2b(v[0]), f2b(v[1]), f2b(v[2]), f2b(v[3]) };
                *(short4*)&Cb[(size_t)row*N + col] = sv;
            }
        }
    }
}

// split-K reduce (bf16 partials) + bias + lrelu + fused BN stats
__global__ void reduce8s(const __hip_bfloat16* __restrict__ part, const float* __restrict__ bias,
                         float* __restrict__ out, int nf4, int parts, float* __restrict__ slots){
    int tid = threadIdx.x;
    int i = blockIdx.x*256 + tid;
    const short4* p4 = (const short4*)part;
    short4 v0 = p4[i];
    float4 s = { b2f(v0.x), b2f(v0.y), b2f(v0.z), b2f(v0.w) };
    for (int z = 1; z < parts; z++){
        short4 p = p4[(size_t)z*nf4 + i];
        s.x += b2f(p.x); s.y += b2f(p.y); s.z += b2f(p.z); s.w += b2f(p.w);
    }
    int c0 = (i & 31) << 2;
    s.x = lrelu(s.x + bias[c0+0]); s.y = lrelu(s.y + bias[c0+1]);
    s.z = lrelu(s.z + bias[c0+2]); s.w = lrelu(s.w + bias[c0+3]);
    ((float4*)out)[i] = s;
    __shared__ float S[128], Q[128];
    if (tid < 128){ S[tid] = 0.f; Q[tid] = 0.f; }
    __syncthreads();
    atomicAdd(&S[c0+0], s.x); atomicAdd(&Q[c0+0], s.x*s.x);
    atomicAdd(&S[c0+1], s.y); atomicAdd(&Q[c0+1], s.y*s.y);
    atomicAdd(&S[c0+2], s.z); atomicAdd(&Q[c0+2], s.z*s.z);
    atomicAdd(&S[c0+3], s.w); atomicAdd(&Q[c0+3], s.w*s.w);
    __syncthreads();
    if (tid < 128){
        int slot = blockIdx.x & (NSLOT-1);
        atomicAdd(&slots[slot*256 + tid], S[tid]);
        atomicAdd(&slots[slot*256 + 128 + tid], Q[tid]);
    }
}

// ---------------------------------------------------------------- final apply: out = y*sc + sh (y bf16)
__global__ __launch_bounds__(256) void final_apply2(
    const bf16x8* __restrict__ yb, const float* __restrict__ coef,
    float4* __restrict__ out, int n8)
{
    int tid = threadIdx.x;
    int c0 = (tid & 15) << 3;
    float sc[8], sh[8];
#pragma unroll
    for (int j = 0; j < 8; j++){ sc[j] = coef[c0+j]; sh[j] = coef[128+c0+j]; }
    int stride = gridDim.x*256;
    for (int i = blockIdx.x*256 + tid; i < n8; i += stride){
        bf16x8 yv = yb[i];
        float4 lo, hi;
        lo.x = b2f(yv[0])*sc[0] + sh[0];
        lo.y = b2f(yv[1])*sc[1] + sh[1];
        lo.z = b2f(yv[2])*sc[2] + sh[2];
        lo.w = b2f(yv[3])*sc[3] + sh[3];
        hi.x = b2f(yv[4])*sc[4] + sh[4];
        hi.y = b2f(yv[5])*sc[5] + sh[5];
        hi.z = b2f(yv[6])*sc[6] + sh[6];
        hi.w = b2f(yv[7])*sc[7] + sh[7];
        out[2*i]   = lo;
        out[2*i+1] = hi;
    }
}

// ---------------------------------------------------------------- BatchNorm
__global__ void bn_stats_v2(const float* __restrict__ x, float* __restrict__ slots, int rows){
    int cg = threadIdx.x & 31, rg = threadIdx.x >> 5;
    float4 s = {0,0,0,0}, q = {0,0,0,0};
    for (int r = blockIdx.x*8 + rg; r < rows; r += gridDim.x*8){
        float4 v = ((const float4*)x)[(size_t)r*32 + cg];
        s.x += v.x; q.x += v.x*v.x;
        s.y += v.y; q.y += v.y*v.y;
        s.z += v.z; q.z += v.z*v.z;
        s.w += v.w; q.w += v.w*v.w;
    }
    __shared__ float S[128], Q[128];
    if (threadIdx.x < 128){ S[threadIdx.x] = 0.f; Q[threadIdx.x] = 0.f; }
    __syncthreads();
    int c0 = cg << 2;
    atomicAdd(&S[c0+0], s.x); atomicAdd(&Q[c0+0], q.x);
    atomicAdd(&S[c0+1], s.y); atomicAdd(&Q[c0+1], q.y);
    atomicAdd(&S[c0+2], s.z); atomicAdd(&Q[c0+2], q.z);
    atomicAdd(&S[c0+3], s.w); atomicAdd(&Q[c0+3], q.w);
    __syncthreads();
    if (threadIdx.x < 128){
        int slot = blockIdx.x & (NSLOT-1);
        atomicAdd(&slots[slot*256 + threadIdx.x], S[threadIdx.x]);
        atomicAdd(&slots[slot*256 + 128 + threadIdx.x], Q[threadIdx.x]);
    }
}

__global__ void bn_finalize2(const float* __restrict__ slots, int nslots,
                             const float* __restrict__ g, const float* __restrict__ b,
                             float invR, float* __restrict__ coef){
    int c = threadIdx.x;
    float s = 0.f, q = 0.f;
    for (int k = 0; k < nslots; k++){ s += slots[k*256 + c]; q += slots[k*256 + 128 + c]; }
    float m = s*invR;
    float v = q*invR - m*m;
    float sc = g[c]*rsqrtf(v + EPSV);
    coef[c] = sc;
    coef[128 + c] = b[c] - m*sc;
}

__global__ void bn_apply4(float4* __restrict__ x, const float* __restrict__ coef, size_t n4){
    size_t i = (size_t)blockIdx.x*blockDim.x + threadIdx.x;
    size_t stride = (size_t)gridDim.x*blockDim.x;
    for (; i < n4; i += stride){
        int c0 = (int)(i & 31) * 4;
        float4 v = x[i];
        v.x = v.x*coef[c0+0] + coef[128+c0+0];
        v.y = v.y*coef[c0+1] + coef[128+c0+1];
        v.z = v.z*coef[c0+2] + coef[128+c0+2];
        v.w = v.w*coef[c0+3] + coef[128+c0+3];
        x[i] = v;
    }
}

// ---------------------------------------------------------------- segment ops
__global__ void seg_sum_edge(const int* __restrict__ eoff, const int* __restrict__ enode,
                             const float* __restrict__ h, float* __restrict__ out){
    int m = blockIdx.x, c = threadIdx.x;
    int s0 = eoff[m], cnt = eoff[m+1] - s0;
    __shared__ int sn[128];
    float acc = 0.f;
    for (int base = 0; base < cnt; base += 128){
        int i = base + c;
        if (i < cnt) sn[c] = enode[s0+i];
        __syncthreads();
        int lim = min(128, cnt - base);
        for (int j = 0; j < lim; j++) acc += h[(size_t)sn[j]*128 + c];
        __syncthreads();
    }
    out[(size_t)m*128 + c] = acc;
}

// heads=4, bf16 features
__global__ void row_att4b(const __hip_bfloat16* __restrict__ xt, const float* __restrict__ att,
                          int aoff, float* __restrict__ out){
    int n = blockIdx.x, lane = threadIdx.x;  // 64
#pragma unroll
    for (int h = 0; h < 4; h++){
        const short* xr = (const short*)(xt + (size_t)n*512 + h*128);
        const float* ar = att + h*256 + aoff;
        unsigned u = *(const unsigned*)(xr + 2*lane);
        float s = b2f((short)(u & 0xffff))*ar[2*lane] + b2f((short)(u >> 16))*ar[2*lane+1];
        for (int d = 32; d > 0; d >>= 1) s += __shfl_down(s, d);
        if (lane == 0) out[n*4 + h] = s;
    }
}

// heads=1, bf16 features
__global__ void row_att1b(const __hip_bfloat16* __restrict__ xt, const float* __restrict__ att,
                          int aoff, float* __restrict__ out){
    int n = blockIdx.x, lane = threadIdx.x;  // 64
    const short* xr = (const short*)(xt + (size_t)n*128);
    const float* ar = att + aoff;
    unsigned u = *(const unsigned*)(xr + 2*lane);
    float s = b2f((short)(u & 0xffff))*ar[2*lane] + b2f((short)(u >> 16))*ar[2*lane+1];
    for (int d = 32; d > 0; d >>= 1) s += __shfl_down(s, d);
    if (lane == 0) out[n] = s;
}

template<int H>
__global__ void seg_softmax(const int* __restrict__ eoff, const int* __restrict__ eperm,
                            const int* __restrict__ enode,
                            const float* __restrict__ ax, const float* __restrict__ ae,
                            float* __restrict__ alpha){
    int m = blockIdx.x, t = threadIdx.x;
    int s0 = eoff[m], cnt = eoff[m+1] - s0;
    if (cnt == 0) return;
    __shared__ float red[128];
    float aeh[H];
#pragma unroll
    for (int h = 0; h < H; h++) aeh[h] = ae[m*H + h];
    float lmax[H];
#pragma unroll
    for (int h = 0; h < H; h++) lmax[h] = -1e30f;
    for (int i = t; i < cnt; i += 128){
        int k = eperm[s0+i]; int n = enode[s0+i];
#pragma unroll
        for (int h = 0; h < H; h++){
            float v = lrelu(ax[n*H + h] + aeh[h]);
            alpha[(size_t)k*H + h] = v;
            lmax[h] = fmaxf(lmax[h], v);
        }
    }
    float gmax[H];
#pragma unroll
    for (int h = 0; h < H; h++){
        red[t] = lmax[h]; __syncthreads();
        for (int s = 64; s > 0; s >>= 1){ if (t < s) red[t] = fmaxf(red[t], red[t+s]); __syncthreads(); }
        gmax[h] = red[0]; __syncthreads();
    }
    float lsum[H];
#pragma unroll
    for (int h = 0; h < H; h++) lsum[h] = 0.f;
    for (int i = t; i < cnt; i += 128){
        int k = eperm[s0+i];
#pragma unroll
        for (int h = 0; h < H; h++){
            float ex = __expf(alpha[(size_t)k*H + h] - gmax[h]);
            alpha[(size_t)k*H + h] = ex;
            lsum[h] += ex;
        }
    }
    float ginv[H];
#pragma unroll
    for (int h = 0; h < H; h++){
        red[t] = lsum[h]; __syncthreads();
        for (int s = 64; s > 0; s >>= 1){ if (t < s) red[t] += red[t+s]; __syncthreads(); }
        ginv[h] = 1.f/red[0]; __syncthreads();
    }
    for (int i = t; i < cnt; i += 128){
        int k = eperm[s0+i];
#pragma unroll
        for (int h = 0; h < H; h++) alpha[(size_t)k*H + h] *= ginv[h];
    }
}

// heads=4, bf16 xt; 256 threads = (head, channel-pair), 4B gathers
__global__ void seg_eo4(const int* __restrict__ eoff, const int* __restrict__ eperm,
                        const int* __restrict__ enode,
                        const float* __restrict__ alpha, const __hip_bfloat16* __restrict__ xt,
                        float* __restrict__ eo){
    int m = blockIdx.x;
    int t = threadIdx.x;
    int h = t >> 6, c2 = t & 63;        // head, channel-pair
    int s0 = eoff[m], cnt = eoff[m+1] - s0;
    __shared__ int sn[128];
    __shared__ float sa[128][4];
    float acc0 = 0.f, acc1 = 0.f;
    for (int base = 0; base < cnt; base += 128){
        int i = base + t;
        if (t < 128 && i < cnt){
            int k = eperm[s0+i];
            sn[t] = enode[s0+i];
#pragma unroll
            for (int hh = 0; hh < 4; hh++) sa[t][hh] = alpha[(size_t)k*4 + hh];
        }
        __syncthreads();
        int lim = min(128, cnt - base);
#pragma unroll 4
        for (int j = 0; j < lim; j++){
            unsigned u = *(const unsigned*)((const short*)xt + (size_t)sn[j]*512 + h*128 + 2*c2);
            float a = sa[j][h];
            acc0 += a * b2f((short)(u & 0xffff));
            acc1 += a * b2f((short)(u >> 16));
        }
        __syncthreads();
    }
    float binv = cnt > 0 ? 1.f/(float)cnt : 0.f;
    float2 st = { acc0*binv, acc1*binv };
    *(float2*)&eo[(size_t)m*512 + h*128 + 2*c2] = st;
}

// heads=1, bf16 xt
__global__ void seg_eo1b(const int* __restrict__ eoff, const int* __restrict__ eperm,
                         const int* __restrict__ enode,
                         const float* __restrict__ alpha, const __hip_bfloat16* __restrict__ xt,
                         float* __restrict__ eo){
    int m = blockIdx.x, c = threadIdx.x;   // 128
    int s0 = eoff[m], cnt = eoff[m+1] - s0;
    __shared__ int sn[128];
    __shared__ float sa[128];
    float acc = 0.f;
    for (int base = 0; base < cnt; base += 128){
        int i = base + c;
        if (i < cnt){
            sn[c] = enode[s0+i];
            sa[c] = alpha[eperm[s0+i]];
        }
        __syncthreads();
        int lim = min(128, cnt - base);
#pragma unroll 4
        for (int j = 0; j < lim; j++)
            acc += sa[j]*b2f(((const short*)xt)[(size_t)sn[j]*128 + c]);
        __syncthreads();
    }
    float binv = cnt > 0 ? 1.f/(float)cnt : 0.f;
    eo[(size_t)m*128 + c] = acc*binv;
}

template<int H>
__global__ void seg_node_out(const int* __restrict__ noff, const int* __restrict__ nperm,
                             const int* __restrict__ nedge,
                             const float* __restrict__ alpha, const float* __restrict__ eo,
                             const float* __restrict__ hin, const float* __restrict__ bias,
                             float* __restrict__ hout){
    int n = blockIdx.x, c = threadIdx.x;
    int s0 = noff[n], cnt = noff[n+1] - s0;
    float acc = 0.f;
    for (int i = 0; i < cnt; i++){
        int k = nperm[s0+i]; int e = nedge[s0+i];
        const float* er = eo + (size_t)e*(128*H);
#pragma unroll
        for (int h = 0; h < H; h++) acc += alpha[(size_t)k*H + h]*er[h*128 + c];
    }
    float dinv = cnt > 0 ? 1.f/((float)cnt*(float)H) : 0.f;
    hout[(size_t)n*128 + c] = hin[(size_t)n*128 + c] + bias[c] + acc*dinv;
}

// ---------------------------------------------------------------- launcher
extern "C" void kernel_launch(void* const* d_in, const int* in_sizes, int n_in,
                              void* d_out, int out_size, void* d_ws, size_t ws_size,
                              hipStream_t stream){
    const float* x    = (const float*)d_in[0];
    const int*   he_n = (const int*)  d_in[1];
    const int*   he_e = (const int*)  d_in[2];
    const float* W1   = (const float*)d_in[3];
    const float* b1   = (const float*)d_in[4];
    const float* g1   = (const float*)d_in[5];
    const float* be1  = (const float*)d_in[6];
    const float* Wh1  = (const float*)d_in[7];
    const float* att1 = (const float*)d_in[8];
    const float* bh1  = (const float*)d_in[9];
    const float* g2   = (const float*)d_in[10];
    const float* be2  = (const float*)d_in[11];
    const float* Wh2  = (const float*)d_in[12];
    const float* att2 = (const float*)d_in[13];
    const float* bh2  = (const float*)d_in[14];
    const float* g3   = (const float*)d_in[15];
    const float* be3  = (const float*)d_in[16];
    const float* W3   = (const float*)d_in[17];
    const float* b3   = (const float*)d_in[18];
    const float* g4   = (const float*)d_in[19];
    const float* be4  = (const float*)d_in[20];
    float* out = (float*)d_out;

    char* ws = (char*)d_ws;
    size_t off = 0;
    auto alloc = [&](size_t bytes)->char*{ char* p = ws + off; off += (bytes + 255) & ~(size_t)255; return p; };

    // big region (64 MB): ybuf (final) aliases part (GEMM1) + xt1b (hconv1)
    char* big = alloc((size_t)NN*DIN*2);
    __hip_bfloat16* ybuf = (__hip_bfloat16*)big;
    __hip_bfloat16* part = (__hip_bfloat16*)big;                          // 16 x 2MB = 32MB
    __hip_bfloat16* xt1b = (__hip_bfloat16*)(big + (size_t)16*NN*128*2);  // 9.4MB at +32MB

    float* hall1  = (float*)alloc((size_t)MALL*128*4);
    float* hall2  = (float*)alloc((size_t)MALL*128*4);
    float* h3     = (float*)alloc((size_t)NN*128*4);
    __hip_bfloat16* xt2b = (__hip_bfloat16*)alloc((size_t)MALL*128*2);
    float* eo     = (float*)alloc((size_t)MME*512*4);
    float* alpha  = (float*)alloc((size_t)NNZK*4*4);
    float* ax     = (float*)alloc((size_t)NN*4*4);
    float* ae     = (float*)alloc((size_t)MME*4*4);
    float* slots  = (float*)alloc((size_t)NSLOT*256*4);
    float* coef   = (float*)alloc(256*4);
    __hip_bfloat16* W1T  = (__hip_bfloat16*)alloc((size_t)128*DIN*2);
    __hip_bfloat16* Wh1T = (__hip_bfloat16*)alloc((size_t)512*128*2);
    __hip_bfloat16* Wh2T = (__hip_bfloat16*)alloc((size_t)128*128*2);
    __hip_bfloat16* W3T  = (__hip_bfloat16*)alloc((size_t)DIN*128*2);
    int* ecnt  = (int*)alloc(MME*4);
    int* ncnt  = (int*)alloc(NN*4);
    int* eoffb = (int*)alloc((MME+1)*4);
    int* ecur  = (int*)alloc(MME*4);
    int* noffb = (int*)alloc((NN+1)*4);
    int* ncur  = (int*)alloc(NN*4);
    int* eperm = (int*)alloc((size_t)NNZK*4);
    int* nperm = (int*)alloc((size_t)NNZK*4);
    int* enode = (int*)alloc((size_t)NNZK*4);
    int* nedge = (int*)alloc((size_t)NNZK*4);

    // ---- CSR build ----
    zero_i<<<(MME+NN+255)/256, 256, 0, stream>>>(ecnt, MME+NN);   // ecnt+ncnt adjacent
    count_seg<<<NNZK/256, 256, 0, stream>>>(he_n, he_e, ncnt, ecnt);
    scan_excl<<<1, 1024, 0, stream>>>(ecnt, eoffb, ecur, MME);
    scan_excl<<<1, 1024, 0, stream>>>(ncnt, noffb, ncur, NN);
    fill_perm2<<<NNZK/256, 256, 0, stream>>>(he_e, he_n, ecur, eperm, enode);
    fill_perm2<<<NNZK/256, 256, 0, stream>>>(he_n, he_e, ncur, nperm, nedge);

    // ---- weight transpose+convert ----
    wconv_t<<<dim3(128/32, DIN/32), 256, 0, stream>>>(W1,  W1T,  DIN, 128);
    wconv_t<<<dim3(512/32, 128/32), 256, 0, stream>>>(Wh1, Wh1T, 128, 512);
    wconv_t<<<dim3(128/32, 128/32), 256, 0, stream>>>(Wh2, Wh2T, 128, 128);
    wconv_t<<<dim3(DIN/32, 128/32), 256, 0, stream>>>(W3,  W3T,  128, DIN);

    // ---- layer 0: h1 = lrelu(x @ W1 + b1); BN1 (stats fused in reduce8s) ----
    gemm_nt<2><<<dim3(1, NN/128, 16), 256, 0, stream>>>(x, W1T, nullptr, part, nullptr, nullptr, nullptr, NN, 128, DIN, DIN/16);
    zero_f<<<NSLOT, 256, 0, stream>>>(slots, NSLOT*256);
    reduce8s<<<NN*128/4/256, 256, 0, stream>>>(part, b1, hall1, NN*128/4, 16, slots);
    bn_finalize2<<<1, 128, 0, stream>>>(slots, NSLOT, g1, be1, 1.f/NN, coef);
    bn_apply4<<<1024, 256, 0, stream>>>((float4*)hall1, coef, (size_t)NN*32);

    // ---- hconv1 (heads=4) ----
    seg_sum_edge<<<MME, 128, 0, stream>>>(eoffb, enode, hall1, hall1 + (size_t)NN*128);
    gemm_nt<5><<<dim3(512/128, MALL/128, 1), 256, 0, stream>>>(hall1, Wh1T, nullptr, xt1b, nullptr, nullptr, nullptr, MALL, 512, 128, 128);
    row_att4b<<<NN, 64, 0, stream>>>(xt1b, att1, 0, ax);
    row_att4b<<<MME, 64, 0, stream>>>(xt1b + (size_t)NN*512, att1, 128, ae);
    seg_softmax<4><<<MME, 128, 0, stream>>>(eoffb, eperm, enode, ax, ae, alpha);
    seg_eo4<<<MME, 256, 0, stream>>>(eoffb, eperm, enode, alpha, xt1b, eo);
    seg_node_out<4><<<NN, 128, 0, stream>>>(noffb, nperm, nedge, alpha, eo, hall1, bh1, hall2);
    zero_f<<<NSLOT, 256, 0, stream>>>(slots, NSLOT*256);
    bn_stats_v2<<<256, 256, 0, stream>>>(hall2, slots, NN);
    bn_finalize2<<<1, 128, 0, stream>>>(slots, NSLOT, g2, be2, 1.f/NN, coef);
    bn_apply4<<<1024, 256, 0, stream>>>((float4*)hall2, coef, (size_t)NN*32);

    // ---- hconv2 (heads=1) ----
    seg_sum_edge<<<MME, 128, 0, stream>>>(eoffb, enode, hall2, hall2 + (size_t)NN*128);
    gemm_nt<5><<<dim3(1, MALL/128, 1), 256, 0, stream>>>(hall2, Wh2T, nullptr, xt2b, nullptr, nullptr, nullptr, MALL, 128, 128, 128);
    row_att1b<<<NN, 64, 0, stream>>>(xt2b, att2, 0, ax);
    row_att1b<<<MME, 64, 0, stream>>>(xt2b + (size_t)NN*128, att2, 128, ae);
    seg_softmax<1><<<MME, 128, 0, stream>>>(eoffb, eperm, enode, ax, ae, alpha);
    seg_eo1b<<<MME, 128, 0, stream>>>(eoffb, eperm, enode, alpha, xt2b, eo);
    seg_node_out<1><<<NN, 128, 0, stream>>>(noffb, nperm, nedge, alpha, eo, hall2, bh2, h3);
    zero_f<<<NSLOT, 256, 0, stream>>>(slots, NSLOT*256);
    bn_stats_v2<<<256, 256, 0, stream>>>(h3, slots, NN);
    bn_finalize2<<<1, 128, 0, stream>>>(slots, NSLOT, g3, be3, 1.f/NN, coef);
    bn_apply4<<<1024, 256, 0, stream>>>((float4*)h3, coef, (size_t)NN*32);

    // ---- final: out = BN4(x + lrelu(h3 @ W3 + b3)), y computed+stat'd in one GEMM ----
    zero_f<<<NSLOT, 256, 0, stream>>>(slots, NSLOT*256);
    gemm_nt<6><<<dim3(DIN/128, NN/128, 1), 256, 0, stream>>>(h3, W3T, nullptr, ybuf, b3, x, slots, NN, DIN, 128, 128);
    bn_finalize2<<<1, 128, 0, stream>>>(slots, NSLOT, g4, be4, 1.f/((float)NN*TT), coef);
    final_apply2<<<2048, 256, 0, stream>>>((const bf16x8*)ybuf, coef, (float4*)out, NN*DIN/8);
}

// Round 9
// 521.246 us; speedup vs baseline: 1.1024x; 1.0559x over previous
//
#include <hip/hip_runtime.h>
#include <hip/hip_bf16.h>
#include <math.h>

#define NN   8192
#define TT   32
#define DIN  4096
#define MME  1024
#define NNZK 131072
#define EPSV 1e-5f
#define MALL (NN + MME)   // 9216 combined node+edge rows
#define NSLOT 8

typedef __attribute__((ext_vector_type(8))) short bf16x8;
typedef __attribute__((ext_vector_type(4))) float f32x4;

__device__ __forceinline__ float lrelu(float v){ return v > 0.f ? v : 0.2f*v; }
__device__ __forceinline__ short f2b(float f){
    union { __hip_bfloat16 h; short s; } u; u.h = __float2bfloat16(f); return u.s;
}
__device__ __forceinline__ float b2f(short s){
    union { float f; unsigned u; } u; u.u = ((unsigned)(unsigned short)s) << 16; return u.f;
}

// ---------------------------------------------------------------- utilities
__global__ void zero_i(int* p, int n){ int i = blockIdx.x*256 + threadIdx.x; if (i < n) p[i] = 0; }
__global__ void zero_f(float* p, int n){ int i = blockIdx.x*256 + threadIdx.x; if (i < n) p[i] = 0.f; }

__global__ void count_seg(const int* __restrict__ he_n, const int* __restrict__ he_e,
                          int* __restrict__ ncnt, int* __restrict__ ecnt){
    int k = blockIdx.x*256 + threadIdx.x;
    if (k < NNZK){ atomicAdd(&ecnt[he_e[k]], 1); atomicAdd(&ncnt[he_n[k]], 1); }
}

// single-block exclusive scan, wave-shuffle based (n multiple of 1024); writes off AND cur
__global__ void scan_excl(const int* __restrict__ cnt, int* __restrict__ off,
                          int* __restrict__ cur, int n){
    int t = threadIdx.x;              // 1024 threads
    int lane = t & 63, wv = t >> 6;   // 16 waves
    int chunk = n >> 10;
    int base = t*chunk;
    int s = 0;
#pragma unroll 4
    for (int i = 0; i < chunk; i++) s += cnt[base+i];
    int v = s;
    for (int d = 1; d < 64; d <<= 1){
        int u = __shfl_up(v, d);
        if (lane >= d) v += u;
    }
    __shared__ int wsum[16];
    if (lane == 63) wsum[wv] = v;
    __syncthreads();
    if (wv == 0 && lane < 16){
        int w2 = wsum[lane];
        for (int d = 1; d < 16; d <<= 1){
            int u = __shfl_up(w2, d);
            if (lane >= d) w2 += u;
        }
        wsum[lane] = w2;
    }
    __syncthreads();
    int excl = v - s + (wv > 0 ? wsum[wv-1] : 0);
    for (int i = 0; i < chunk; i++){
        off[base+i] = excl;
        cur[base+i] = excl;
        excl += cnt[base+i];
    }
    if (t == 1023) off[n] = excl;
}

// perm fill that also materializes the sorted "other endpoint" array
__global__ void fill_perm2(const int* __restrict__ seg, const int* __restrict__ other,
                           int* __restrict__ cur, int* __restrict__ perm, int* __restrict__ oth){
    int k = blockIdx.x*256 + threadIdx.x;
    if (k < NNZK){
        int p = atomicAdd(&cur[seg[k]], 1);
        perm[p] = k;
        oth[p] = other[k];
    }
}

// ---------------------------------------------------------------- x -> bf16 stream
__global__ __launch_bounds__(256) void convert_x(const float4* __restrict__ x,
                                                 bf16x8* __restrict__ xb, int n8){
    int stride = gridDim.x*256;
    for (int i = blockIdx.x*256 + threadIdx.x; i < n8; i += stride){
        float4 lo = x[2*i], hi = x[2*i+1];
        bf16x8 v;
        v[0]=f2b(lo.x); v[1]=f2b(lo.y); v[2]=f2b(lo.z); v[3]=f2b(lo.w);
        v[4]=f2b(hi.x); v[5]=f2b(hi.y); v[6]=f2b(hi.z); v[7]=f2b(hi.w);
        xb[i] = v;
    }
}

// ------------------------------------------------ weight convert + transpose
__global__ void wconv_t(const float* __restrict__ W, __hip_bfloat16* __restrict__ BT, int K, int N){
    __shared__ float tile[32][33];
    int k0 = blockIdx.y*32, n0 = blockIdx.x*32;
    int tx = threadIdx.x & 31, ty = threadIdx.x >> 5;
    for (int i = ty; i < 32; i += 8) tile[i][tx] = W[(size_t)(k0+i)*N + n0+tx];
    __syncthreads();
    for (int i = ty; i < 32; i += 8)
        BT[(size_t)(n0+i)*K + k0 + tx] = __float2bfloat16(tile[tx][i]);
}

#define SWZ(b) ((b) ^ ((((b) >> 6) & 7) << 4))

// ---------------------------------------------------------------- all-bf16 GEMM (GEMM1)
// C_slice_z[M,N](bf16) = Ab[M,K] @ Bwt^T  (both bf16 K-major), split-K over blockIdx.z
__global__ __launch_bounds__(256) void gemm_bb(
    const __hip_bfloat16* __restrict__ Ab, const __hip_bfloat16* __restrict__ Bwt,
    __hip_bfloat16* __restrict__ Cb, int M, int N, int K, int kchunk)
{
    __shared__ f32x4 WsRaw[512];   // 8 KB
    __shared__ f32x4 XsRaw[512];   // 8 KB
    char* Ws = (char*)WsRaw;
    char* Xs = (char*)XsRaw;
    const int tid = threadIdx.x;
    const int lane = tid & 63;
    const int w = tid >> 6;
    const int m0 = blockIdx.y << 7, n0 = blockIdx.x << 7;
    const int kz = blockIdx.z * kchunk;
    const int wN = (w >> 1) << 6, wM = (w & 1) << 6;

    const int s0 = tid, s1 = tid + 256;
    const int r0 = s0 >> 2, k0b = (s0 & 3) << 3;
    const int r1 = s1 >> 2, k1b = (s1 & 3) << 3;
    const __hip_bfloat16* pA0 = Ab + (size_t)(m0 + r0)*K + kz + k0b;
    const __hip_bfloat16* pA1 = Ab + (size_t)(m0 + r1)*K + kz + k1b;
    const __hip_bfloat16* pW0 = Bwt + (size_t)(n0 + r0)*K + kz + k0b;
    const __hip_bfloat16* pW1 = Bwt + (size_t)(n0 + r1)*K + kz + k1b;
    const int wo0 = SWZ(s0 << 4), wo1 = SWZ(s1 << 4);

    int rwOff[4], rxOff[4];
#pragma unroll
    for (int f = 0; f < 4; f++){
        rwOff[f] = SWZ((wN + f*16 + (lane & 15))*64 + ((lane >> 4) << 4));
        rxOff[f] = SWZ((wM + f*16 + (lane & 15))*64 + ((lane >> 4) << 4));
    }

    f32x4 acc[4][4] = {};

    bf16x8 a0 = *(const bf16x8*)pA0, a1 = *(const bf16x8*)pA1;
    bf16x8 w0 = *(const bf16x8*)pW0, w1 = *(const bf16x8*)pW1;

    const int nsteps = kchunk >> 5;
    for (int ks = 0; ks < nsteps; ks++){
        __syncthreads();
        *(bf16x8*)(Xs + wo0) = a0;
        *(bf16x8*)(Xs + wo1) = a1;
        *(bf16x8*)(Ws + wo0) = w0;
        *(bf16x8*)(Ws + wo1) = w1;
        __syncthreads();
        if (ks + 1 < nsteps){
            pA0 += 32; pA1 += 32; pW0 += 32; pW1 += 32;
            a0 = *(const bf16x8*)pA0; a1 = *(const bf16x8*)pA1;
            w0 = *(const bf16x8*)pW0; w1 = *(const bf16x8*)pW1;
        }
        bf16x8 wf[4], xf[4];
#pragma unroll
        for (int f = 0; f < 4; f++){
            wf[f] = *(const bf16x8*)(Ws + rwOff[f]);
            xf[f] = *(const bf16x8*)(Xs + rxOff[f]);
        }
#pragma unroll
        for (int i = 0; i < 4; i++)
#pragma unroll
            for (int j = 0; j < 4; j++)
                acc[i][j] = __builtin_amdgcn_mfma_f32_16x16x32_bf16(wf[i], xf[j], acc[i][j], 0, 0, 0);
    }

    const int mc = wM + (lane & 15);
    const int ncb = wN + ((lane >> 4) << 2);
    __hip_bfloat16* Cz = Cb + (size_t)blockIdx.z * ((size_t)M * (size_t)N);
#pragma unroll
    for (int j = 0; j < 4; j++){
        int row = m0 + mc + j*16;
#pragma unroll
        for (int i = 0; i < 4; i++){
            int col = n0 + ncb + i*16;
            f32x4 v = acc[i][j];
            short4 sv = { f2b(v[0]), f2b(v[1]), f2b(v[2]), f2b(v[3]) };
            *(short4*)&Cz[(size_t)row*N + col] = sv;
        }
    }
}

// ---------------------------------------------------------------- MFMA GEMM (fp32 A, swapped orientation)
// MODE 5: plain bf16 store
// MODE 7: A-staging folds BN (v*sc[k]+sh[k], coefA), epilogue lrelu(acc+bias) -> bf16 store
template<int MODE>
__global__ __launch_bounds__(256) void gemm_nt(
    const float* __restrict__ Aact, const __hip_bfloat16* __restrict__ Bwt,
    __hip_bfloat16* __restrict__ Cb, const float* __restrict__ bias,
    const float* __restrict__ coefA, int M, int N, int K, int kchunk)
{
    __shared__ f32x4 WsRaw[512];   // 8 KB
    __shared__ f32x4 XsRaw[512];   // 8 KB
    char* Ws = (char*)WsRaw;
    char* Xs = (char*)XsRaw;
    const int tid = threadIdx.x;
    const int lane = tid & 63;
    const int w = tid >> 6;
    const int m0 = blockIdx.y << 7, n0 = blockIdx.x << 7;
    const int wN = (w >> 1) << 6, wM = (w & 1) << 6;

    const int s0 = tid, s1 = tid + 256;
    const int r0 = s0 >> 2, k0b = (s0 & 3) << 3;
    const int r1 = s1 >> 2, k1b = (s1 & 3) << 3;
    const float* pX0 = Aact + (size_t)(m0 + r0)*K + k0b;
    const float* pX1 = Aact + (size_t)(m0 + r1)*K + k1b;
    const __hip_bfloat16* pW0 = Bwt + (size_t)(n0 + r0)*K + k0b;
    const __hip_bfloat16* pW1 = Bwt + (size_t)(n0 + r1)*K + k1b;
    const int wo0 = SWZ(s0 << 4), wo1 = SWZ(s1 << 4);

    int rwOff[4], rxOff[4];
#pragma unroll
    for (int f = 0; f < 4; f++){
        rwOff[f] = SWZ((wN + f*16 + (lane & 15))*64 + ((lane >> 4) << 4));
        rxOff[f] = SWZ((wM + f*16 + (lane & 15))*64 + ((lane >> 4) << 4));
    }

    f32x4 acc[4][4] = {};

    float4 x0l = *(const float4*)pX0, x0h = *(const float4*)(pX0+4);
    float4 x1l = *(const float4*)pX1, x1h = *(const float4*)(pX1+4);
    bf16x8 w0 = *(const bf16x8*)pW0, w1 = *(const bf16x8*)pW1;

    const int nsteps = kchunk >> 5;
    for (int ks = 0; ks < nsteps; ks++){
        if (MODE == 7){
            int kc0 = k0b + ks*32, kc1 = k1b + ks*32;
            float4 s0v = *(const float4*)&coefA[kc0],     s0w = *(const float4*)&coefA[kc0+4];
            float4 h0v = *(const float4*)&coefA[128+kc0], h0w = *(const float4*)&coefA[128+kc0+4];
            float4 s1v = *(const float4*)&coefA[kc1],     s1w = *(const float4*)&coefA[kc1+4];
            float4 h1v = *(const float4*)&coefA[128+kc1], h1w = *(const float4*)&coefA[128+kc1+4];
            x0l.x = x0l.x*s0v.x + h0v.x; x0l.y = x0l.y*s0v.y + h0v.y;
            x0l.z = x0l.z*s0v.z + h0v.z; x0l.w = x0l.w*s0v.w + h0v.w;
            x0h.x = x0h.x*s0w.x + h0w.x; x0h.y = x0h.y*s0w.y + h0w.y;
            x0h.z = x0h.z*s0w.z + h0w.z; x0h.w = x0h.w*s0w.w + h0w.w;
            x1l.x = x1l.x*s1v.x + h1v.x; x1l.y = x1l.y*s1v.y + h1v.y;
            x1l.z = x1l.z*s1v.z + h1v.z; x1l.w = x1l.w*s1v.w + h1v.w;
            x1h.x = x1h.x*s1w.x + h1w.x; x1h.y = x1h.y*s1w.y + h1w.y;
            x1h.z = x1h.z*s1w.z + h1w.z; x1h.w = x1h.w*s1w.w + h1w.w;
        }
        bf16x8 vx0, vx1;
        vx0[0]=f2b(x0l.x); vx0[1]=f2b(x0l.y); vx0[2]=f2b(x0l.z); vx0[3]=f2b(x0l.w);
        vx0[4]=f2b(x0h.x); vx0[5]=f2b(x0h.y); vx0[6]=f2b(x0h.z); vx0[7]=f2b(x0h.w);
        vx1[0]=f2b(x1l.x); vx1[1]=f2b(x1l.y); vx1[2]=f2b(x1l.z); vx1[3]=f2b(x1l.w);
        vx1[4]=f2b(x1h.x); vx1[5]=f2b(x1h.y); vx1[6]=f2b(x1h.z); vx1[7]=f2b(x1h.w);
        __syncthreads();
        *(bf16x8*)(Xs + wo0) = vx0;
        *(bf16x8*)(Xs + wo1) = vx1;
        *(bf16x8*)(Ws + wo0) = w0;
        *(bf16x8*)(Ws + wo1) = w1;
        __syncthreads();
        if (ks + 1 < nsteps){
            pX0 += 32; pX1 += 32; pW0 += 32; pW1 += 32;
            x0l = *(const float4*)pX0; x0h = *(const float4*)(pX0+4);
            x1l = *(const float4*)pX1; x1h = *(const float4*)(pX1+4);
            w0 = *(const bf16x8*)pW0;  w1 = *(const bf16x8*)pW1;
        }
        bf16x8 wf[4], xf[4];
#pragma unroll
        for (int f = 0; f < 4; f++){
            wf[f] = *(const bf16x8*)(Ws + rwOff[f]);
            xf[f] = *(const bf16x8*)(Xs + rxOff[f]);
        }
#pragma unroll
        for (int i = 0; i < 4; i++)
#pragma unroll
            for (int j = 0; j < 4; j++)
                acc[i][j] = __builtin_amdgcn_mfma_f32_16x16x32_bf16(wf[i], xf[j], acc[i][j], 0, 0, 0);
    }

    const int mc = wM + (lane & 15);
    const int ncb = wN + ((lane >> 4) << 2);
#pragma unroll
    for (int j = 0; j < 4; j++){
        int row = m0 + mc + j*16;
#pragma unroll
        for (int i = 0; i < 4; i++){
            int col = n0 + ncb + i*16;
            f32x4 v = acc[i][j];
            if (MODE == 7){
                float4 b4 = *(const float4*)&bias[col];
                short4 sv = { f2b(lrelu(v[0] + b4.x)), f2b(lrelu(v[1] + b4.y)),
                              f2b(lrelu(v[2] + b4.z)), f2b(lrelu(v[3] + b4.w)) };
                *(short4*)&Cb[(size_t)row*N + col] = sv;
            } else {  // MODE 5
                short4 sv = { f2b(v[0]), f2b(v[1]), f2b(v[2]), f2b(v[3]) };
                *(short4*)&Cb[(size_t)row*N + col] = sv;
            }
        }
    }
}

// split-K reduce (bf16 partials) + bias + lrelu + fused BN stats
__global__ void reduce8s(const __hip_bfloat16* __restrict__ part, const float* __restrict__ bias,
                         float* __restrict__ out, int nf4, int parts, float* __restrict__ slots){
    int tid = threadIdx.x;
    int i = blockIdx.x*256 + tid;
    const short4* p4 = (const short4*)part;
    short4 v0 = p4[i];
    float4 s = { b2f(v0.x), b2f(v0.y), b2f(v0.z), b2f(v0.w) };
    for (int z = 1; z < parts; z++){
        short4 p = p4[(size_t)z*nf4 + i];
        s.x += b2f(p.x); s.y += b2f(p.y); s.z += b2f(p.z); s.w += b2f(p.w);
    }
    int c0 = (i & 31) << 2;
    s.x = lrelu(s.x + bias[c0+0]); s.y = lrelu(s.y + bias[c0+1]);
    s.z = lrelu(s.z + bias[c0+2]); s.w = lrelu(s.w + bias[c0+3]);
    ((float4*)out)[i] = s;
    __shared__ float S[128], Q[128];
    if (tid < 128){ S[tid] = 0.f; Q[tid] = 0.f; }
    __syncthreads();
    atomicAdd(&S[c0+0], s.x); atomicAdd(&Q[c0+0], s.x*s.x);
    atomicAdd(&S[c0+1], s.y); atomicAdd(&Q[c0+1], s.y*s.y);
    atomicAdd(&S[c0+2], s.z); atomicAdd(&Q[c0+2], s.z*s.z);
    atomicAdd(&S[c0+3], s.w); atomicAdd(&Q[c0+3], s.w*s.w);
    __syncthreads();
    if (tid < 128){
        int slot = blockIdx.x & (NSLOT-1);
        atomicAdd(&slots[slot*256 + tid], S[tid]);
        atomicAdd(&slots[slot*256 + 128 + tid], Q[tid]);
    }
}

// ---------------------------------------------------------------- final stage streaming (bf16 reads)
__global__ __launch_bounds__(256) void final_stats(
    const bf16x8* __restrict__ xb, const bf16x8* __restrict__ f,
    float* __restrict__ slots, int n8)
{
    int tid = threadIdx.x;
    float s[8] = {0,0,0,0,0,0,0,0}, q[8] = {0,0,0,0,0,0,0,0};
    int stride = gridDim.x*256;
    for (int i = blockIdx.x*256 + tid; i < n8; i += stride){
        bf16x8 xv = xb[i], fv = f[i];
#pragma unroll
        for (int j = 0; j < 8; j++){
            float y = b2f(xv[j]) + b2f(fv[j]);
            s[j] += y; q[j] += y*y;
        }
    }
    __shared__ float S[128], Q[128];
    if (tid < 128){ S[tid] = 0.f; Q[tid] = 0.f; }
    __syncthreads();
    int c0 = (tid & 15) << 3;
#pragma unroll
    for (int j = 0; j < 8; j++){
        atomicAdd(&S[c0+j], s[j]);
        atomicAdd(&Q[c0+j], q[j]);
    }
    __syncthreads();
    if (tid < 128){
        int slot = blockIdx.x & (NSLOT-1);
        atomicAdd(&slots[slot*256 + tid], S[tid]);
        atomicAdd(&slots[slot*256 + 128 + tid], Q[tid]);
    }
}

__global__ __launch_bounds__(256) void final_apply(
    const bf16x8* __restrict__ xb, const bf16x8* __restrict__ f,
    const float* __restrict__ coef, float4* __restrict__ out, int n8)
{
    int tid = threadIdx.x;
    int c0 = (tid & 15) << 3;
    float sc[8], sh[8];
#pragma unroll
    for (int j = 0; j < 8; j++){ sc[j] = coef[c0+j]; sh[j] = coef[128+c0+j]; }
    int stride = gridDim.x*256;
    for (int i = blockIdx.x*256 + tid; i < n8; i += stride){
        bf16x8 xv = xb[i], fv = f[i];
        float4 lo, hi;
        lo.x = (b2f(xv[0]) + b2f(fv[0]))*sc[0] + sh[0];
        lo.y = (b2f(xv[1]) + b2f(fv[1]))*sc[1] + sh[1];
        lo.z = (b2f(xv[2]) + b2f(fv[2]))*sc[2] + sh[2];
        lo.w = (b2f(xv[3]) + b2f(fv[3]))*sc[3] + sh[3];
        hi.x = (b2f(xv[4]) + b2f(fv[4]))*sc[4] + sh[4];
        hi.y = (b2f(xv[5]) + b2f(fv[5]))*sc[5] + sh[5];
        hi.z = (b2f(xv[6]) + b2f(fv[6]))*sc[6] + sh[6];
        hi.w = (b2f(xv[7]) + b2f(fv[7]))*sc[7] + sh[7];
        out[2*i]   = lo;
        out[2*i+1] = hi;
    }
}

// ---------------------------------------------------------------- BatchNorm
__global__ void bn_stats_v2(const float* __restrict__ x, float* __restrict__ slots, int rows){
    int cg = threadIdx.x & 31, rg = threadIdx.x >> 5;
    float4 s = {0,0,0,0}, q = {0,0,0,0};
    for (int r = blockIdx.x*8 + rg; r < rows; r += gridDim.x*8){
        float4 v = ((const float4*)x)[(size_t)r*32 + cg];
        s.x += v.x; q.x += v.x*v.x;
        s.y += v.y; q.y += v.y*v.y;
        s.z += v.z; q.z += v.z*v.z;
        s.w += v.w; q.w += v.w*v.w;
    }
    __shared__ float S[128], Q[128];
    if (threadIdx.x < 128){ S[threadIdx.x] = 0.f; Q[threadIdx.x] = 0.f; }
    __syncthreads();
    int c0 = cg << 2;
    atomicAdd(&S[c0+0], s.x); atomicAdd(&Q[c0+0], q.x);
    atomicAdd(&S[c0+1], s.y); atomicAdd(&Q[c0+1], q.y);
    atomicAdd(&S[c0+2], s.z); atomicAdd(&Q[c0+2], q.z);
    atomicAdd(&S[c0+3], s.w); atomicAdd(&Q[c0+3], q.w);
    __syncthreads();
    if (threadIdx.x < 128){
        int slot = blockIdx.x & (NSLOT-1);
        atomicAdd(&slots[slot*256 + threadIdx.x], S[threadIdx.x]);
        atomicAdd(&slots[slot*256 + 128 + threadIdx.x], Q[threadIdx.x]);
    }
}

__global__ void bn_finalize2(const float* __restrict__ slots, int nslots,
                             const float* __restrict__ g, const float* __restrict__ b,
                             float invR, float* __restrict__ coef){
    int c = threadIdx.x;
    float s = 0.f, q = 0.f;
    for (int k = 0; k < nslots; k++){ s += slots[k*256 + c]; q += slots[k*256 + 128 + c]; }
    float m = s*invR;
    float v = q*invR - m*m;
    float sc = g[c]*rsqrtf(v + EPSV);
    coef[c] = sc;
    coef[128 + c] = b[c] - m*sc;
}

__global__ void bn_apply4(float4* __restrict__ x, const float* __restrict__ coef, size_t n4){
    size_t i = (size_t)blockIdx.x*blockDim.x + threadIdx.x;
    size_t stride = (size_t)gridDim.x*blockDim.x;
    for (; i < n4; i += stride){
        int c0 = (int)(i & 31) * 4;
        float4 v = x[i];
        v.x = v.x*coef[c0+0] + coef[128+c0+0];
        v.y = v.y*coef[c0+1] + coef[128+c0+1];
        v.z = v.z*coef[c0+2] + coef[128+c0+2];
        v.w = v.w*coef[c0+3] + coef[128+c0+3];
        x[i] = v;
    }
}

// ---------------------------------------------------------------- segment ops
__global__ void seg_sum_edge(const int* __restrict__ eoff, const int* __restrict__ enode,
                             const float* __restrict__ h, float* __restrict__ out){
    int m = blockIdx.x, c = threadIdx.x;
    int s0 = eoff[m], cnt = eoff[m+1] - s0;
    __shared__ int sn[128];
    float acc = 0.f;
    for (int base = 0; base < cnt; base += 128){
        int i = base + c;
        if (i < cnt) sn[c] = enode[s0+i];
        __syncthreads();
        int lim = min(128, cnt - base);
        for (int j = 0; j < lim; j++) acc += h[(size_t)sn[j]*128 + c];
        __syncthreads();
    }
    out[(size_t)m*128 + c] = acc;
}

// heads=4, bf16 features
__global__ void row_att4b(const __hip_bfloat16* __restrict__ xt, const float* __restrict__ att,
                          int aoff, float* __restrict__ out){
    int n = blockIdx.x, lane = threadIdx.x;  // 64
#pragma unroll
    for (int h = 0; h < 4; h++){
        const short* xr = (const short*)(xt + (size_t)n*512 + h*128);
        const float* ar = att + h*256 + aoff;
        unsigned u = *(const unsigned*)(xr + 2*lane);
        float s = b2f((short)(u & 0xffff))*ar[2*lane] + b2f((short)(u >> 16))*ar[2*lane+1];
        for (int d = 32; d > 0; d >>= 1) s += __shfl_down(s, d);
        if (lane == 0) out[n*4 + h] = s;
    }
}

// heads=1, bf16 features
__global__ void row_att1b(const __hip_bfloat16* __restrict__ xt, const float* __restrict__ att,
                          int aoff, float* __restrict__ out){
    int n = blockIdx.x, lane = threadIdx.x;  // 64
    const short* xr = (const short*)(xt + (size_t)n*128);
    const float* ar = att + aoff;
    unsigned u = *(const unsigned*)(xr + 2*lane);
    float s = b2f((short)(u & 0xffff))*ar[2*lane] + b2f((short)(u >> 16))*ar[2*lane+1];
    for (int d = 32; d > 0; d >>= 1) s += __shfl_down(s, d);
    if (lane == 0) out[n] = s;
}

template<int H>
__global__ void seg_softmax(const int* __restrict__ eoff, const int* __restrict__ eperm,
                            const int* __restrict__ enode,
                            const float* __restrict__ ax, const float* __restrict__ ae,
                            float* __restrict__ alpha){
    int m = blockIdx.x, t = threadIdx.x;
    int s0 = eoff[m], cnt = eoff[m+1] - s0;
    if (cnt == 0) return;
    __shared__ float red[128];
    float aeh[H];
#pragma unroll
    for (int h = 0; h < H; h++) aeh[h] = ae[m*H + h];
    float lmax[H];
#pragma unroll
    for (int h = 0; h < H; h++) lmax[h] = -1e30f;
    for (int i = t; i < cnt; i += 128){
        int k = eperm[s0+i]; int n = enode[s0+i];
#pragma unroll
        for (int h = 0; h < H; h++){
            float v = lrelu(ax[n*H + h] + aeh[h]);
            alpha[(size_t)k*H + h] = v;
            lmax[h] = fmaxf(lmax[h], v);
        }
    }
    float gmax[H];
#pragma unroll
    for (int h = 0; h < H; h++){
        red[t] = lmax[h]; __syncthreads();
        for (int s = 64; s > 0; s >>= 1){ if (t < s) red[t] = fmaxf(red[t], red[t+s]); __syncthreads(); }
        gmax[h] = red[0]; __syncthreads();
    }
    float lsum[H];
#pragma unroll
    for (int h = 0; h < H; h++) lsum[h] = 0.f;
    for (int i = t; i < cnt; i += 128){
        int k = eperm[s0+i];
#pragma unroll
        for (int h = 0; h < H; h++){
            float ex = __expf(alpha[(size_t)k*H + h] - gmax[h]);
            alpha[(size_t)k*H + h] = ex;
            lsum[h] += ex;
        }
    }
    float ginv[H];
#pragma unroll
    for (int h = 0; h < H; h++){
        red[t] = lsum[h]; __syncthreads();
        for (int s = 64; s > 0; s >>= 1){ if (t < s) red[t] += red[t+s]; __syncthreads(); }
        ginv[h] = 1.f/red[0]; __syncthreads();
    }
    for (int i = t; i < cnt; i += 128){
        int k = eperm[s0+i];
#pragma unroll
        for (int h = 0; h < H; h++) alpha[(size_t)k*H + h] *= ginv[h];
    }
}

// heads=4, bf16 xt; 256 threads = (head, channel-pair), 4B gathers
__global__ void seg_eo4(const int* __restrict__ eoff, const int* __restrict__ eperm,
                        const int* __restrict__ enode,
                        const float* __restrict__ alpha, const __hip_bfloat16* __restrict__ xt,
                        float* __restrict__ eo){
    int m = blockIdx.x;
    int t = threadIdx.x;
    int h = t >> 6, c2 = t & 63;        // head, channel-pair
    int s0 = eoff[m], cnt = eoff[m+1] - s0;
    __shared__ int sn[128];
    __shared__ float sa[128][4];
    float acc0 = 0.f, acc1 = 0.f;
    for (int base = 0; base < cnt; base += 128){
        int i = base + t;
        if (t < 128 && i < cnt){
            int k = eperm[s0+i];
            sn[t] = enode[s0+i];
#pragma unroll
            for (int hh = 0; hh < 4; hh++) sa[t][hh] = alpha[(size_t)k*4 + hh];
        }
        __syncthreads();
        int lim = min(128, cnt - base);
#pragma unroll 4
        for (int j = 0; j < lim; j++){
            unsigned u = *(const unsigned*)((const short*)xt + (size_t)sn[j]*512 + h*128 + 2*c2);
            float a = sa[j][h];
            acc0 += a * b2f((short)(u & 0xffff));
            acc1 += a * b2f((short)(u >> 16));
        }
        __syncthreads();
    }
    float binv = cnt > 0 ? 1.f/(float)cnt : 0.f;
    float2 st = { acc0*binv, acc1*binv };
    *(float2*)&eo[(size_t)m*512 + h*128 + 2*c2] = st;
}

// heads=1, bf16 xt
__global__ void seg_eo1b(const int* __restrict__ eoff, const int* __restrict__ eperm,
                         const int* __restrict__ enode,
                         const float* __restrict__ alpha, const __hip_bfloat16* __restrict__ xt,
                         float* __restrict__ eo){
    int m = blockIdx.x, c = threadIdx.x;   // 128
    int s0 = eoff[m], cnt = eoff[m+1] - s0;
    __shared__ int sn[128];
    __shared__ float sa[128];
    float acc = 0.f;
    for (int base = 0; base < cnt; base += 128){
        int i = base + c;
        if (i < cnt){
            sn[c] = enode[s0+i];
            sa[c] = alpha[eperm[s0+i]];
        }
        __syncthreads();
        int lim = min(128, cnt - base);
#pragma unroll 4
        for (int j = 0; j < lim; j++)
            acc += sa[j]*b2f(((const short*)xt)[(size_t)sn[j]*128 + c]);
        __syncthreads();
    }
    float binv = cnt > 0 ? 1.f/(float)cnt : 0.f;
    eo[(size_t)m*128 + c] = acc*binv;
}

template<int H>
__global__ void seg_node_out(const int* __restrict__ noff, const int* __restrict__ nperm,
                             const int* __restrict__ nedge,
                             const float* __restrict__ alpha, const float* __restrict__ eo,
                             const float* __restrict__ hin, const float* __restrict__ bias,
                             float* __restrict__ hout){
    int n = blockIdx.x, c = threadIdx.x;
    int s0 = noff[n], cnt = noff[n+1] - s0;
    float acc = 0.f;
    for (int i = 0; i < cnt; i++){
        int k = nperm[s0+i]; int e = nedge[s0+i];
        const float* er = eo + (size_t)e*(128*H);
#pragma unroll
        for (int h = 0; h < H; h++) acc += alpha[(size_t)k*H + h]*er[h*128 + c];
    }
    float dinv = cnt > 0 ? 1.f/((float)cnt*(float)H) : 0.f;
    hout[(size_t)n*128 + c] = hin[(size_t)n*128 + c] + bias[c] + acc*dinv;
}

// ---------------------------------------------------------------- launcher
extern "C" void kernel_launch(void* const* d_in, const int* in_sizes, int n_in,
                              void* d_out, int out_size, void* d_ws, size_t ws_size,
                              hipStream_t stream){
    const float* x    = (const float*)d_in[0];
    const int*   he_n = (const int*)  d_in[1];
    const int*   he_e = (const int*)  d_in[2];
    const float* W1   = (const float*)d_in[3];
    const float* b1   = (const float*)d_in[4];
    const float* g1   = (const float*)d_in[5];
    const float* be1  = (const float*)d_in[6];
    const float* Wh1  = (const float*)d_in[7];
    const float* att1 = (const float*)d_in[8];
    const float* bh1  = (const float*)d_in[9];
    const float* g2   = (const float*)d_in[10];
    const float* be2  = (const float*)d_in[11];
    const float* Wh2  = (const float*)d_in[12];
    const float* att2 = (const float*)d_in[13];
    const float* bh2  = (const float*)d_in[14];
    const float* g3   = (const float*)d_in[15];
    const float* be3  = (const float*)d_in[16];
    const float* W3   = (const float*)d_in[17];
    const float* b3   = (const float*)d_in[18];
    const float* g4   = (const float*)d_in[19];
    const float* be4  = (const float*)d_in[20];
    float* out = (float*)d_out;

    char* ws = (char*)d_ws;
    size_t off = 0;
    auto alloc = [&](size_t bytes)->char*{ char* p = ws + off; off += (bytes + 255) & ~(size_t)255; return p; };

    // big region (64 MB): fbuf (final) aliases part (GEMM1) + xt1b (hconv1)
    char* big = alloc((size_t)NN*DIN*2);
    __hip_bfloat16* fbuf = (__hip_bfloat16*)big;
    __hip_bfloat16* part = (__hip_bfloat16*)big;                          // 16 x 2MB = 32MB
    __hip_bfloat16* xt1b = (__hip_bfloat16*)(big + (size_t)16*NN*128*2);  // 9.4MB at +32MB
    __hip_bfloat16* xbuf = (__hip_bfloat16*)alloc((size_t)NN*DIN*2);      // bf16 x (64MB), lives whole pass

    float* hall1  = (float*)alloc((size_t)MALL*128*4);
    float* hall2  = (float*)alloc((size_t)MALL*128*4);
    float* h3     = (float*)alloc((size_t)NN*128*4);
    __hip_bfloat16* xt2b = (__hip_bfloat16*)alloc((size_t)MALL*128*2);
    float* eo     = (float*)alloc((size_t)MME*512*4);
    float* alpha  = (float*)alloc((size_t)NNZK*4*4);
    float* ax     = (float*)alloc((size_t)NN*4*4);
    float* ae     = (float*)alloc((size_t)MME*4*4);
    float* slots  = (float*)alloc((size_t)NSLOT*256*4);
    float* coef   = (float*)alloc(256*4);
    __hip_bfloat16* W1T  = (__hip_bfloat16*)alloc((size_t)128*DIN*2);
    __hip_bfloat16* Wh1T = (__hip_bfloat16*)alloc((size_t)512*128*2);
    __hip_bfloat16* Wh2T = (__hip_bfloat16*)alloc((size_t)128*128*2);
    __hip_bfloat16* W3T  = (__hip_bfloat16*)alloc((size_t)DIN*128*2);
    int* ecnt  = (int*)alloc(MME*4);
    int* ncnt  = (int*)alloc(NN*4);
    int* eoffb = (int*)alloc((MME+1)*4);
    int* ecur  = (int*)alloc(MME*4);
    int* noffb = (int*)alloc((NN+1)*4);
    int* ncur  = (int*)alloc(NN*4);
    int* eperm = (int*)alloc((size_t)NNZK*4);
    int* nperm = (int*)alloc((size_t)NNZK*4);
    int* enode = (int*)alloc((size_t)NNZK*4);
    int* nedge = (int*)alloc((size_t)NNZK*4);

    // ---- x -> bf16 (one stream pass; consumers: gemm_bb, final_stats, final_apply) ----
    convert_x<<<2048, 256, 0, stream>>>((const float4*)x, (bf16x8*)xbuf, NN*DIN/8);

    // ---- CSR build ----
    zero_i<<<(MME+NN+255)/256, 256, 0, stream>>>(ecnt, MME+NN);   // ecnt+ncnt adjacent
    count_seg<<<NNZK/256, 256, 0, stream>>>(he_n, he_e, ncnt, ecnt);
    scan_excl<<<1, 1024, 0, stream>>>(ecnt, eoffb, ecur, MME);
    scan_excl<<<1, 1024, 0, stream>>>(ncnt, noffb, ncur, NN);
    fill_perm2<<<NNZK/256, 256, 0, stream>>>(he_e, he_n, ecur, eperm, enode);
    fill_perm2<<<NNZK/256, 256, 0, stream>>>(he_n, he_e, ncur, nperm, nedge);

    // ---- weight transpose+convert ----
    wconv_t<<<dim3(128/32, DIN/32), 256, 0, stream>>>(W1,  W1T,  DIN, 128);
    wconv_t<<<dim3(512/32, 128/32), 256, 0, stream>>>(Wh1, Wh1T, 128, 512);
    wconv_t<<<dim3(128/32, 128/32), 256, 0, stream>>>(Wh2, Wh2T, 128, 128);
    wconv_t<<<dim3(DIN/32, 128/32), 256, 0, stream>>>(W3,  W3T,  128, DIN);

    // ---- layer 0: h1 = lrelu(xb @ W1 + b1); BN1 (stats fused in reduce8s) ----
    gemm_bb<<<dim3(1, NN/128, 16), 256, 0, stream>>>(xbuf, W1T, part, NN, 128, DIN, DIN/16);
    zero_f<<<NSLOT, 256, 0, stream>>>(slots, NSLOT*256);
    reduce8s<<<NN*128/4/256, 256, 0, stream>>>(part, b1, hall1, NN*128/4, 16, slots);
    bn_finalize2<<<1, 128, 0, stream>>>(slots, NSLOT, g1, be1, 1.f/NN, coef);
    bn_apply4<<<1024, 256, 0, stream>>>((float4*)hall1, coef, (size_t)NN*32);

    // ---- hconv1 (heads=4) ----
    seg_sum_edge<<<MME, 128, 0, stream>>>(eoffb, enode, hall1, hall1 + (size_t)NN*128);
    gemm_nt<5><<<dim3(512/128, MALL/128, 1), 256, 0, stream>>>(hall1, Wh1T, xt1b, nullptr, nullptr, MALL, 512, 128, 128);
    row_att4b<<<NN, 64, 0, stream>>>(xt1b, att1, 0, ax);
    row_att4b<<<MME, 64, 0, stream>>>(xt1b + (size_t)NN*512, att1, 128, ae);
    seg_softmax<4><<<MME, 128, 0, stream>>>(eoffb, eperm, enode, ax, ae, alpha);
    seg_eo4<<<MME, 256, 0, stream>>>(eoffb, eperm, enode, alpha, xt1b, eo);
    seg_node_out<4><<<NN, 128, 0, stream>>>(noffb, nperm, nedge, alpha, eo, hall1, bh1, hall2);
    zero_f<<<NSLOT, 256, 0, stream>>>(slots, NSLOT*256);
    bn_stats_v2<<<256, 256, 0, stream>>>(hall2, slots, NN);
    bn_finalize2<<<1, 128, 0, stream>>>(slots, NSLOT, g2, be2, 1.f/NN, coef);
    bn_apply4<<<1024, 256, 0, stream>>>((float4*)hall2, coef, (size_t)NN*32);

    // ---- hconv2 (heads=1) ----
    seg_sum_edge<<<MME, 128, 0, stream>>>(eoffb, enode, hall2, hall2 + (size_t)NN*128);
    gemm_nt<5><<<dim3(1, MALL/128, 1), 256, 0, stream>>>(hall2, Wh2T, xt2b, nullptr, nullptr, MALL, 128, 128, 128);
    row_att1b<<<NN, 64, 0, stream>>>(xt2b, att2, 0, ax);
    row_att1b<<<MME, 64, 0, stream>>>(xt2b + (size_t)NN*128, att2, 128, ae);
    seg_softmax<1><<<MME, 128, 0, stream>>>(eoffb, eperm, enode, ax, ae, alpha);
    seg_eo1b<<<MME, 128, 0, stream>>>(eoffb, eperm, enode, alpha, xt2b, eo);
    seg_node_out<1><<<NN, 128, 0, stream>>>(noffb, nperm, nedge, alpha, eo, hall2, bh2, h3);

    // ---- BN3: stats only; apply folded into GEMM3 staging ----
    zero_f<<<NSLOT, 256, 0, stream>>>(slots, NSLOT*256);
    bn_stats_v2<<<256, 256, 0, stream>>>(h3, slots, NN);
    bn_finalize2<<<1, 128, 0, stream>>>(slots, NSLOT, g3, be3, 1.f/NN, coef);

    // ---- final: out = BN4(x + lrelu(BN3(h3) @ W3 + b3)) ----
    gemm_nt<7><<<dim3(DIN/128, NN/128, 1), 256, 0, stream>>>(h3, W3T, fbuf, b3, coef, NN, DIN, 128, 128);
    zero_f<<<NSLOT, 256, 0, stream>>>(slots, NSLOT*256);
    final_stats<<<2048, 256, 0, stream>>>((const bf16x8*)xbuf, (const bf16x8*)fbuf, slots, NN*DIN/8);
    bn_finalize2<<<1, 128, 0, stream>>>(slots, NSLOT, g4, be4, 1.f/((float)NN*TT), coef);
    final_apply<<<2048, 256, 0, stream>>>((const bf16x8*)xbuf, (const bf16x8*)fbuf, coef, (float4*)out, NN*DIN/8);
}

// Round 10
// 490.025 us; speedup vs baseline: 1.1727x; 1.0637x over previous
//
#include <hip/hip_runtime.h>
#include <hip/hip_bf16.h>
#include <math.h>

#define NN   8192
#define TT   32
#define DIN  4096
#define MME  1024
#define NNZK 131072
#define EPSV 1e-5f
#define MALL (NN + MME)
#define NSLOT 8

typedef __attribute__((ext_vector_type(8))) short bf16x8;
typedef __attribute__((ext_vector_type(4))) float f32x4;

__device__ __forceinline__ float lrelu(float v){ return v > 0.f ? v : 0.2f*v; }
__device__ __forceinline__ short f2b(float f){
    union { __hip_bfloat16 h; short s; } u; u.h = __float2bfloat16(f); return u.s;
}
__device__ __forceinline__ float b2f(short s){
    union { float f; unsigned u; } u; u.u = ((unsigned)(unsigned short)s) << 16; return u.f;
}

// ---------------------------------------------------------------- utilities
__global__ void zero_i(int* p, int n){ int i = blockIdx.x*256 + threadIdx.x; if (i < n) p[i] = 0; }
__global__ void zero_f(float* p, int n){ int i = blockIdx.x*256 + threadIdx.x; if (i < n) p[i] = 0.f; }

__global__ void count_seg(const int* __restrict__ he_n, const int* __restrict__ he_e,
                          int* __restrict__ ncnt, int* __restrict__ ecnt){
    int k = blockIdx.x*256 + threadIdx.x;
    if (k < NNZK){ atomicAdd(&ecnt[he_e[k]], 1); atomicAdd(&ncnt[he_n[k]], 1); }
}

// wave-shuffle exclusive scan body (1024 threads, n multiple of 1024)
__device__ void scan_body(const int* __restrict__ cnt, int* __restrict__ off,
                          int* __restrict__ cur, int n){
    int t = threadIdx.x;
    int lane = t & 63, wv = t >> 6;
    int chunk = n >> 10;
    int base = t*chunk;
    int s = 0;
#pragma unroll 4
    for (int i = 0; i < chunk; i++) s += cnt[base+i];
    int v = s;
    for (int d = 1; d < 64; d <<= 1){
        int u = __shfl_up(v, d);
        if (lane >= d) v += u;
    }
    __shared__ int wsum[16];
    if (lane == 63) wsum[wv] = v;
    __syncthreads();
    if (wv == 0 && lane < 16){
        int w2 = wsum[lane];
        for (int d = 1; d < 16; d <<= 1){
            int u = __shfl_up(w2, d);
            if (lane >= d) w2 += u;
        }
        wsum[lane] = w2;
    }
    __syncthreads();
    int excl = v - s + (wv > 0 ? wsum[wv-1] : 0);
    for (int i = 0; i < chunk; i++){
        off[base+i] = excl;
        cur[base+i] = excl;
        excl += cnt[base+i];
    }
    if (t == 1023) off[n] = excl;
}

__global__ void scan2(const int* ecnt, int* eoffb, int* ecur,
                      const int* ncnt, int* noffb, int* ncur){
    if (blockIdx.x == 0) scan_body(ecnt, eoffb, ecur, MME);
    else                 scan_body(ncnt, noffb, ncur, NN);
}

// both scatters in one pass
__global__ void fill_both(const int* __restrict__ he_n, const int* __restrict__ he_e,
                          int* __restrict__ ecur, int* __restrict__ ncur,
                          int* __restrict__ eperm, int* __restrict__ enode,
                          int* __restrict__ nperm, int* __restrict__ nedge){
    int k = blockIdx.x*256 + threadIdx.x;
    if (k < NNZK){
        int e = he_e[k], n = he_n[k];
        int p = atomicAdd(&ecur[e], 1); eperm[p] = k; enode[p] = n;
        int q = atomicAdd(&ncur[n], 1); nperm[q] = k; nedge[q] = e;
    }
}

// ---------------------------------------------------------------- x -> bf16 stream
__global__ __launch_bounds__(256) void convert_x(const float4* __restrict__ x,
                                                 bf16x8* __restrict__ xb, int n8){
    int stride = gridDim.x*256;
    for (int i = blockIdx.x*256 + threadIdx.x; i < n8; i += stride){
        float4 lo = x[2*i], hi = x[2*i+1];
        bf16x8 v;
        v[0]=f2b(lo.x); v[1]=f2b(lo.y); v[2]=f2b(lo.z); v[3]=f2b(lo.w);
        v[4]=f2b(hi.x); v[5]=f2b(hi.y); v[6]=f2b(hi.z); v[7]=f2b(hi.w);
        xb[i] = v;
    }
}

// ------------------------------------------------ all weight converts, one launch
__device__ void wconv_body(const float* __restrict__ W, __hip_bfloat16* __restrict__ BT,
                           int K, int N, int gx, int gy){
    __shared__ float tile[32][33];
    int k0 = gy*32, n0 = gx*32;
    int tx = threadIdx.x & 31, ty = threadIdx.x >> 5;
    for (int i = ty; i < 32; i += 8) tile[i][tx] = W[(size_t)(k0+i)*N + n0+tx];
    __syncthreads();
    for (int i = ty; i < 32; i += 8)
        BT[(size_t)(n0+i)*K + k0 + tx] = __float2bfloat16(tile[tx][i]);
}

__global__ void wconv_all(const float* W1, __hip_bfloat16* W1T,
                          const float* Wh1, __hip_bfloat16* Wh1T,
                          const float* Wh2, __hip_bfloat16* Wh2T,
                          const float* W3, __hip_bfloat16* W3T){
    int b = blockIdx.x;
    if (b < 512)            wconv_body(W1,  W1T,  DIN, 128, b % 4,          b / 4);
    else if (b < 576){ b -= 512; wconv_body(Wh1, Wh1T, 128, 512, b % 16, b / 16); }
    else if (b < 592){ b -= 576; wconv_body(Wh2, Wh2T, 128, 128, b % 4,  b / 4); }
    else             { b -= 592; wconv_body(W3,  W3T,  128, DIN, b % 128, b / 128); }
}

#define SWZ(b) ((b) ^ ((((b) >> 6) & 7) << 4))

// ---------------------------------------------------------------- all-bf16 GEMM (GEMM1)
__global__ __launch_bounds__(256) void gemm_bb(
    const __hip_bfloat16* __restrict__ Ab, const __hip_bfloat16* __restrict__ Bwt,
    __hip_bfloat16* __restrict__ Cb, int M, int N, int K, int kchunk)
{
    __shared__ f32x4 WsRaw[512];
    __shared__ f32x4 XsRaw[512];
    char* Ws = (char*)WsRaw;
    char* Xs = (char*)XsRaw;
    const int tid = threadIdx.x;
    const int lane = tid & 63;
    const int w = tid >> 6;
    const int m0 = blockIdx.y << 7, n0 = blockIdx.x << 7;
    const int kz = blockIdx.z * kchunk;
    const int wN = (w >> 1) << 6, wM = (w & 1) << 6;

    const int s0 = tid, s1 = tid + 256;
    const int r0 = s0 >> 2, k0b = (s0 & 3) << 3;
    const int r1 = s1 >> 2, k1b = (s1 & 3) << 3;
    const __hip_bfloat16* pA0 = Ab + (size_t)(m0 + r0)*K + kz + k0b;
    const __hip_bfloat16* pA1 = Ab + (size_t)(m0 + r1)*K + kz + k1b;
    const __hip_bfloat16* pW0 = Bwt + (size_t)(n0 + r0)*K + kz + k0b;
    const __hip_bfloat16* pW1 = Bwt + (size_t)(n0 + r1)*K + kz + k1b;
    const int wo0 = SWZ(s0 << 4), wo1 = SWZ(s1 << 4);

    int rwOff[4], rxOff[4];
#pragma unroll
    for (int f = 0; f < 4; f++){
        rwOff[f] = SWZ((wN + f*16 + (lane & 15))*64 + ((lane >> 4) << 4));
        rxOff[f] = SWZ((wM + f*16 + (lane & 15))*64 + ((lane >> 4) << 4));
    }

    f32x4 acc[4][4] = {};

    bf16x8 a0 = *(const bf16x8*)pA0, a1 = *(const bf16x8*)pA1;
    bf16x8 w0 = *(const bf16x8*)pW0, w1 = *(const bf16x8*)pW1;

    const int nsteps = kchunk >> 5;
    for (int ks = 0; ks < nsteps; ks++){
        __syncthreads();
        *(bf16x8*)(Xs + wo0) = a0;
        *(bf16x8*)(Xs + wo1) = a1;
        *(bf16x8*)(Ws + wo0) = w0;
        *(bf16x8*)(Ws + wo1) = w1;
        __syncthreads();
        if (ks + 1 < nsteps){
            pA0 += 32; pA1 += 32; pW0 += 32; pW1 += 32;
            a0 = *(const bf16x8*)pA0; a1 = *(const bf16x8*)pA1;
            w0 = *(const bf16x8*)pW0; w1 = *(const bf16x8*)pW1;
        }
        bf16x8 wf[4], xf[4];
#pragma unroll
        for (int f = 0; f < 4; f++){
            wf[f] = *(const bf16x8*)(Ws + rwOff[f]);
            xf[f] = *(const bf16x8*)(Xs + rxOff[f]);
        }
#pragma unroll
        for (int i = 0; i < 4; i++)
#pragma unroll
            for (int j = 0; j < 4; j++)
                acc[i][j] = __builtin_amdgcn_mfma_f32_16x16x32_bf16(wf[i], xf[j], acc[i][j], 0, 0, 0);
    }

    const int mc = wM + (lane & 15);
    const int ncb = wN + ((lane >> 4) << 2);
    __hip_bfloat16* Cz = Cb + (size_t)blockIdx.z * ((size_t)M * (size_t)N);
#pragma unroll
    for (int j = 0; j < 4; j++){
        int row = m0 + mc + j*16;
#pragma unroll
        for (int i = 0; i < 4; i++){
            int col = n0 + ncb + i*16;
            f32x4 v = acc[i][j];
            short4 sv = { f2b(v[0]), f2b(v[1]), f2b(v[2]), f2b(v[3]) };
            *(short4*)&Cz[(size_t)row*N + col] = sv;
        }
    }
}

// ---------------------------------------------------------------- GEMM with fused row-attention dot
// bf16 store + per-row dot with att slice (block = one head's 128 channels)
template<int H>
__global__ __launch_bounds__(256) void gemm_att(
    const float* __restrict__ Aact, const __hip_bfloat16* __restrict__ Bwt,
    __hip_bfloat16* __restrict__ Cb, const float* __restrict__ attv,
    float* __restrict__ axo, float* __restrict__ aeo, int M, int N, int K)
{
    __shared__ f32x4 WsRaw[512];
    __shared__ f32x4 XsRaw[512];
    __shared__ float sAx[128];
    char* Ws = (char*)WsRaw;
    char* Xs = (char*)XsRaw;
    const int tid = threadIdx.x;
    const int lane = tid & 63;
    const int w = tid >> 6;
    const int m0 = blockIdx.y << 7, n0 = blockIdx.x << 7;
    const int wN = (w >> 1) << 6, wM = (w & 1) << 6;

    const int s0 = tid, s1 = tid + 256;
    const int r0 = s0 >> 2, k0b = (s0 & 3) << 3;
    const int r1 = s1 >> 2, k1b = (s1 & 3) << 3;
    const float* pX0 = Aact + (size_t)(m0 + r0)*K + k0b;
    const float* pX1 = Aact + (size_t)(m0 + r1)*K + k1b;
    const __hip_bfloat16* pW0 = Bwt + (size_t)(n0 + r0)*K + k0b;
    const __hip_bfloat16* pW1 = Bwt + (size_t)(n0 + r1)*K + k1b;
    const int wo0 = SWZ(s0 << 4), wo1 = SWZ(s1 << 4);

    int rwOff[4], rxOff[4];
#pragma unroll
    for (int f = 0; f < 4; f++){
        rwOff[f] = SWZ((wN + f*16 + (lane & 15))*64 + ((lane >> 4) << 4));
        rxOff[f] = SWZ((wM + f*16 + (lane & 15))*64 + ((lane >> 4) << 4));
    }

    f32x4 acc[4][4] = {};

    float4 x0l = *(const float4*)pX0, x0h = *(const float4*)(pX0+4);
    float4 x1l = *(const float4*)pX1, x1h = *(const float4*)(pX1+4);
    bf16x8 w0 = *(const bf16x8*)pW0, w1 = *(const bf16x8*)pW1;

    const int nsteps = K >> 5;
    for (int ks = 0; ks < nsteps; ks++){
        bf16x8 vx0, vx1;
        vx0[0]=f2b(x0l.x); vx0[1]=f2b(x0l.y); vx0[2]=f2b(x0l.z); vx0[3]=f2b(x0l.w);
        vx0[4]=f2b(x0h.x); vx0[5]=f2b(x0h.y); vx0[6]=f2b(x0h.z); vx0[7]=f2b(x0h.w);
        vx1[0]=f2b(x1l.x); vx1[1]=f2b(x1l.y); vx1[2]=f2b(x1l.z); vx1[3]=f2b(x1l.w);
        vx1[4]=f2b(x1h.x); vx1[5]=f2b(x1h.y); vx1[6]=f2b(x1h.z); vx1[7]=f2b(x1h.w);
        __syncthreads();
        *(bf16x8*)(Xs + wo0) = vx0;
        *(bf16x8*)(Xs + wo1) = vx1;
        *(bf16x8*)(Ws + wo0) = w0;
        *(bf16x8*)(Ws + wo1) = w1;
        __syncthreads();
        if (ks + 1 < nsteps){
            pX0 += 32; pX1 += 32; pW0 += 32; pW1 += 32;
            x0l = *(const float4*)pX0; x0h = *(const float4*)(pX0+4);
            x1l = *(const float4*)pX1; x1h = *(const float4*)(pX1+4);
            w0 = *(const bf16x8*)pW0;  w1 = *(const bf16x8*)pW1;
        }
        bf16x8 wf[4], xf[4];
#pragma unroll
        for (int f = 0; f < 4; f++){
            wf[f] = *(const bf16x8*)(Ws + rwOff[f]);
            xf[f] = *(const bf16x8*)(Xs + rxOff[f]);
        }
#pragma unroll
        for (int i = 0; i < 4; i++)
#pragma unroll
            for (int j = 0; j < 4; j++)
                acc[i][j] = __builtin_amdgcn_mfma_f32_16x16x32_bf16(wf[i], xf[j], acc[i][j], 0, 0, 0);
    }

    const int mc = wM + (lane & 15);
    const int ncb = wN + ((lane >> 4) << 2);
    if (tid < 128) sAx[tid] = 0.f;
    __syncthreads();
    const int h = blockIdx.x;                 // block = one head's channel window
    const int aoff = (m0 >= NN) ? 128 : 0;
    const float* av = attv + h*256 + aoff;
    float4 a4[4];
#pragma unroll
    for (int i = 0; i < 4; i++) a4[i] = *(const float4*)&av[ncb + i*16];
    float sj[4] = {0.f, 0.f, 0.f, 0.f};
#pragma unroll
    for (int j = 0; j < 4; j++){
        int row = m0 + mc + j*16;
#pragma unroll
        for (int i = 0; i < 4; i++){
            int col = n0 + ncb + i*16;
            f32x4 v = acc[i][j];
            short4 sv = { f2b(v[0]), f2b(v[1]), f2b(v[2]), f2b(v[3]) };
            *(short4*)&Cb[(size_t)row*N + col] = sv;
            sj[j] += v[0]*a4[i].x + v[1]*a4[i].y + v[2]*a4[i].z + v[3]*a4[i].w;
        }
    }
#pragma unroll
    for (int j = 0; j < 4; j++) atomicAdd(&sAx[mc + j*16], sj[j]);
    __syncthreads();
    if (tid < 128){
        int row = m0 + tid;
        float val = sAx[tid];
        if (row < NN) axo[row*H + h] = val;
        else          aeo[(row - NN)*H + h] = val;
    }
}

// ---------------------------------------------------------------- MFMA GEMM (fp32 A), MODE 7: BN fold in staging
__global__ __launch_bounds__(256) void gemm_nt7(
    const float* __restrict__ Aact, const __hip_bfloat16* __restrict__ Bwt,
    __hip_bfloat16* __restrict__ Cb, const float* __restrict__ bias,
    const float* __restrict__ coefA, int M, int N, int K)
{
    __shared__ f32x4 WsRaw[512];
    __shared__ f32x4 XsRaw[512];
    char* Ws = (char*)WsRaw;
    char* Xs = (char*)XsRaw;
    const int tid = threadIdx.x;
    const int lane = tid & 63;
    const int w = tid >> 6;
    const int m0 = blockIdx.y << 7, n0 = blockIdx.x << 7;
    const int wN = (w >> 1) << 6, wM = (w & 1) << 6;

    const int s0 = tid, s1 = tid + 256;
    const int r0 = s0 >> 2, k0b = (s0 & 3) << 3;
    const int r1 = s1 >> 2, k1b = (s1 & 3) << 3;
    const float* pX0 = Aact + (size_t)(m0 + r0)*K + k0b;
    const float* pX1 = Aact + (size_t)(m0 + r1)*K + k1b;
    const __hip_bfloat16* pW0 = Bwt + (size_t)(n0 + r0)*K + k0b;
    const __hip_bfloat16* pW1 = Bwt + (size_t)(n0 + r1)*K + k1b;
    const int wo0 = SWZ(s0 << 4), wo1 = SWZ(s1 << 4);

    int rwOff[4], rxOff[4];
#pragma unroll
    for (int f = 0; f < 4; f++){
        rwOff[f] = SWZ((wN + f*16 + (lane & 15))*64 + ((lane >> 4) << 4));
        rxOff[f] = SWZ((wM + f*16 + (lane & 15))*64 + ((lane >> 4) << 4));
    }

    f32x4 acc[4][4] = {};

    float4 x0l = *(const float4*)pX0, x0h = *(const float4*)(pX0+4);
    float4 x1l = *(const float4*)pX1, x1h = *(const float4*)(pX1+4);
    bf16x8 w0 = *(const bf16x8*)pW0, w1 = *(const bf16x8*)pW1;

    const int nsteps = K >> 5;
    for (int ks = 0; ks < nsteps; ks++){
        int kc0 = k0b + ks*32, kc1 = k1b + ks*32;
        float4 s0v = *(const float4*)&coefA[kc0],     s0w = *(const float4*)&coefA[kc0+4];
        float4 h0v = *(const float4*)&coefA[128+kc0], h0w = *(const float4*)&coefA[128+kc0+4];
        float4 s1v = *(const float4*)&coefA[kc1],     s1w = *(const float4*)&coefA[kc1+4];
        float4 h1v = *(const float4*)&coefA[128+kc1], h1w = *(const float4*)&coefA[128+kc1+4];
        x0l.x = x0l.x*s0v.x + h0v.x; x0l.y = x0l.y*s0v.y + h0v.y;
        x0l.z = x0l.z*s0v.z + h0v.z; x0l.w = x0l.w*s0v.w + h0v.w;
        x0h.x = x0h.x*s0w.x + h0w.x; x0h.y = x0h.y*s0w.y + h0w.y;
        x0h.z = x0h.z*s0w.z + h0w.z; x0h.w = x0h.w*s0w.w + h0w.w;
        x1l.x = x1l.x*s1v.x + h1v.x; x1l.y = x1l.y*s1v.y + h1v.y;
        x1l.z = x1l.z*s1v.z + h1v.z; x1l.w = x1l.w*s1v.w + h1v.w;
        x1h.x = x1h.x*s1w.x + h1w.x; x1h.y = x1h.y*s1w.y + h1w.y;
        x1h.z = x1h.z*s1w.z + h1w.z; x1h.w = x1h.w*s1w.w + h1w.w;
        bf16x8 vx0, vx1;
        vx0[0]=f2b(x0l.x); vx0[1]=f2b(x0l.y); vx0[2]=f2b(x0l.z); vx0[3]=f2b(x0l.w);
        vx0[4]=f2b(x0h.x); vx0[5]=f2b(x0h.y); vx0[6]=f2b(x0h.z); vx0[7]=f2b(x0h.w);
        vx1[0]=f2b(x1l.x); vx1[1]=f2b(x1l.y); vx1[2]=f2b(x1l.z); vx1[3]=f2b(x1l.w);
        vx1[4]=f2b(x1h.x); vx1[5]=f2b(x1h.y); vx1[6]=f2b(x1h.z); vx1[7]=f2b(x1h.w);
        __syncthreads();
        *(bf16x8*)(Xs + wo0) = vx0;
        *(bf16x8*)(Xs + wo1) = vx1;
        *(bf16x8*)(Ws + wo0) = w0;
        *(bf16x8*)(Ws + wo1) = w1;
        __syncthreads();
        if (ks + 1 < nsteps){
            pX0 += 32; pX1 += 32; pW0 += 32; pW1 += 32;
            x0l = *(const float4*)pX0; x0h = *(const float4*)(pX0+4);
            x1l = *(const float4*)pX1; x1h = *(const float4*)(pX1+4);
            w0 = *(const bf16x8*)pW0;  w1 = *(const bf16x8*)pW1;
        }
        bf16x8 wf[4], xf[4];
#pragma unroll
        for (int f = 0; f < 4; f++){
            wf[f] = *(const bf16x8*)(Ws + rwOff[f]);
            xf[f] = *(const bf16x8*)(Xs + rxOff[f]);
        }
#pragma unroll
        for (int i = 0; i < 4; i++)
#pragma unroll
            for (int j = 0; j < 4; j++)
                acc[i][j] = __builtin_amdgcn_mfma_f32_16x16x32_bf16(wf[i], xf[j], acc[i][j], 0, 0, 0);
    }

    const int mc = wM + (lane & 15);
    const int ncb = wN + ((lane >> 4) << 2);
#pragma unroll
    for (int j = 0; j < 4; j++){
        int row = m0 + mc + j*16;
#pragma unroll
        for (int i = 0; i < 4; i++){
            int col = n0 + ncb + i*16;
            f32x4 v = acc[i][j];
            float4 b4 = *(const float4*)&bias[col];
            short4 sv = { f2b(lrelu(v[0] + b4.x)), f2b(lrelu(v[1] + b4.y)),
                          f2b(lrelu(v[2] + b4.z)), f2b(lrelu(v[3] + b4.w)) };
            *(short4*)&Cb[(size_t)row*N + col] = sv;
        }
    }
}

// split-K reduce (bf16 partials) + bias + lrelu + fused BN stats
__global__ void reduce8s(const __hip_bfloat16* __restrict__ part, const float* __restrict__ bias,
                         float* __restrict__ out, int nf4, int parts, float* __restrict__ slots){
    int tid = threadIdx.x;
    int i = blockIdx.x*256 + tid;
    const short4* p4 = (const short4*)part;
    short4 v0 = p4[i];
    float4 s = { b2f(v0.x), b2f(v0.y), b2f(v0.z), b2f(v0.w) };
    for (int z = 1; z < parts; z++){
        short4 p = p4[(size_t)z*nf4 + i];
        s.x += b2f(p.x); s.y += b2f(p.y); s.z += b2f(p.z); s.w += b2f(p.w);
    }
    int c0 = (i & 31) << 2;
    s.x = lrelu(s.x + bias[c0+0]); s.y = lrelu(s.y + bias[c0+1]);
    s.z = lrelu(s.z + bias[c0+2]); s.w = lrelu(s.w + bias[c0+3]);
    ((float4*)out)[i] = s;
    __shared__ float S[128], Q[128];
    if (tid < 128){ S[tid] = 0.f; Q[tid] = 0.f; }
    __syncthreads();
    atomicAdd(&S[c0+0], s.x); atomicAdd(&Q[c0+0], s.x*s.x);
    atomicAdd(&S[c0+1], s.y); atomicAdd(&Q[c0+1], s.y*s.y);
    atomicAdd(&S[c0+2], s.z); atomicAdd(&Q[c0+2], s.z*s.z);
    atomicAdd(&S[c0+3], s.w); atomicAdd(&Q[c0+3], s.w*s.w);
    __syncthreads();
    if (tid < 128){
        int slot = blockIdx.x & (NSLOT-1);
        atomicAdd(&slots[slot*256 + tid], S[tid]);
        atomicAdd(&slots[slot*256 + 128 + tid], Q[tid]);
    }
}

// ---------------------------------------------------------------- final stage streaming
__global__ __launch_bounds__(256) void final_stats(
    const bf16x8* __restrict__ xb, const bf16x8* __restrict__ f,
    float* __restrict__ slots, int n8)
{
    int tid = threadIdx.x;
    float s[8] = {0,0,0,0,0,0,0,0}, q[8] = {0,0,0,0,0,0,0,0};
    int stride = gridDim.x*256;
    for (int i = blockIdx.x*256 + tid; i < n8; i += stride){
        bf16x8 xv = xb[i], fv = f[i];
#pragma unroll
        for (int j = 0; j < 8; j++){
            float y = b2f(xv[j]) + b2f(fv[j]);
            s[j] += y; q[j] += y*y;
        }
    }
    __shared__ float S[128], Q[128];
    if (tid < 128){ S[tid] = 0.f; Q[tid] = 0.f; }
    __syncthreads();
    int c0 = (tid & 15) << 3;
#pragma unroll
    for (int j = 0; j < 8; j++){
        atomicAdd(&S[c0+j], s[j]);
        atomicAdd(&Q[c0+j], q[j]);
    }
    __syncthreads();
    if (tid < 128){
        int slot = blockIdx.x & (NSLOT-1);
        atomicAdd(&slots[slot*256 + tid], S[tid]);
        atomicAdd(&slots[slot*256 + 128 + tid], Q[tid]);
    }
}

__global__ __launch_bounds__(256) void final_apply(
    const bf16x8* __restrict__ xb, const bf16x8* __restrict__ f,
    const float* __restrict__ coef, float4* __restrict__ out, int n8)
{
    int tid = threadIdx.x;
    int c0 = (tid & 15) << 3;
    float sc[8], sh[8];
#pragma unroll
    for (int j = 0; j < 8; j++){ sc[j] = coef[c0+j]; sh[j] = coef[128+c0+j]; }
    int stride = gridDim.x*256;
    for (int i = blockIdx.x*256 + tid; i < n8; i += stride){
        bf16x8 xv = xb[i], fv = f[i];
        float4 lo, hi;
        lo.x = (b2f(xv[0]) + b2f(fv[0]))*sc[0] + sh[0];
        lo.y = (b2f(xv[1]) + b2f(fv[1]))*sc[1] + sh[1];
        lo.z = (b2f(xv[2]) + b2f(fv[2]))*sc[2] + sh[2];
        lo.w = (b2f(xv[3]) + b2f(fv[3]))*sc[3] + sh[3];
        hi.x = (b2f(xv[4]) + b2f(fv[4]))*sc[4] + sh[4];
        hi.y = (b2f(xv[5]) + b2f(fv[5]))*sc[5] + sh[5];
        hi.z = (b2f(xv[6]) + b2f(fv[6]))*sc[6] + sh[6];
        hi.w = (b2f(xv[7]) + b2f(fv[7]))*sc[7] + sh[7];
        out[2*i]   = lo;
        out[2*i+1] = hi;
    }
}

// ---------------------------------------------------------------- BatchNorm
__global__ void bn_stats_v2(const float* __restrict__ x, float* __restrict__ slots, int rows){
    int cg = threadIdx.x & 31, rg = threadIdx.x >> 5;
    float4 s = {0,0,0,0}, q = {0,0,0,0};
    for (int r = blockIdx.x*8 + rg; r < rows; r += gridDim.x*8){
        float4 v = ((const float4*)x)[(size_t)r*32 + cg];
        s.x += v.x; q.x += v.x*v.x;
        s.y += v.y; q.y += v.y*v.y;
        s.z += v.z; q.z += v.z*v.z;
        s.w += v.w; q.w += v.w*v.w;
    }
    __shared__ float S[128], Q[128];
    if (threadIdx.x < 128){ S[threadIdx.x] = 0.f; Q[threadIdx.x] = 0.f; }
    __syncthreads();
    int c0 = cg << 2;
    atomicAdd(&S[c0+0], s.x); atomicAdd(&Q[c0+0], q.x);
    atomicAdd(&S[c0+1], s.y); atomicAdd(&Q[c0+1], q.y);
    atomicAdd(&S[c0+2], s.z); atomicAdd(&Q[c0+2], q.z);
    atomicAdd(&S[c0+3], s.w); atomicAdd(&Q[c0+3], q.w);
    __syncthreads();
    if (threadIdx.x < 128){
        int slot = blockIdx.x & (NSLOT-1);
        atomicAdd(&slots[slot*256 + threadIdx.x], S[threadIdx.x]);
        atomicAdd(&slots[slot*256 + 128 + threadIdx.x], Q[threadIdx.x]);
    }
}

// finalize + re-zero slots for next use
__global__ void bn_finalize2z(float* __restrict__ slots, int nslots,
                              const float* __restrict__ g, const float* __restrict__ b,
                              float invR, float* __restrict__ coef){
    int c = threadIdx.x;
    float s = 0.f, q = 0.f;
    for (int k = 0; k < nslots; k++){
        s += slots[k*256 + c]; q += slots[k*256 + 128 + c];
        slots[k*256 + c] = 0.f; slots[k*256 + 128 + c] = 0.f;
    }
    float m = s*invR;
    float v = q*invR - m*m;
    float sc = g[c]*rsqrtf(v + EPSV);
    coef[c] = sc;
    coef[128 + c] = b[c] - m*sc;
}

__global__ void bn_apply4(float4* __restrict__ x, const float* __restrict__ coef, size_t n4){
    size_t i = (size_t)blockIdx.x*blockDim.x + threadIdx.x;
    size_t stride = (size_t)gridDim.x*blockDim.x;
    for (; i < n4; i += stride){
        int c0 = (int)(i & 31) * 4;
        float4 v = x[i];
        v.x = v.x*coef[c0+0] + coef[128+c0+0];
        v.y = v.y*coef[c0+1] + coef[128+c0+1];
        v.z = v.z*coef[c0+2] + coef[128+c0+2];
        v.w = v.w*coef[c0+3] + coef[128+c0+3];
        x[i] = v;
    }
}

// ---------------------------------------------------------------- segment ops (widened gathers)
// float4 loads, 4 rows/iter, LDS combine
__global__ void seg_sum_edge(const int* __restrict__ eoff, const int* __restrict__ enode,
                             const float* __restrict__ h, float* __restrict__ out){
    int m = blockIdx.x, t = threadIdx.x;   // 128
    int jg = t >> 5, cq = t & 31;
    int s0 = eoff[m], cnt = eoff[m+1] - s0;
    __shared__ int sn[128];
    __shared__ float4 comb[4][32];
    float4 acc = {0,0,0,0};
    for (int base = 0; base < cnt; base += 128){
        int i = base + t;
        if (i < cnt) sn[t] = enode[s0+i];
        __syncthreads();
        int lim = min(128, cnt - base);
        for (int j = jg; j < lim; j += 4){
            float4 v = *(const float4*)&h[(size_t)sn[j]*128 + cq*4];
            acc.x += v.x; acc.y += v.y; acc.z += v.z; acc.w += v.w;
        }
        __syncthreads();
    }
    comb[jg][cq] = acc;
    __syncthreads();
    if (t < 32){
        float4 a = comb[0][t], b = comb[1][t], c = comb[2][t], d = comb[3][t];
        float4 tot = { a.x+b.x+c.x+d.x, a.y+b.y+c.y+d.y, a.z+b.z+c.z+d.z, a.w+b.w+c.w+d.w };
        *(float4*)&out[(size_t)m*128 + t*4] = tot;
    }
}

template<int H>
__global__ void seg_softmax(const int* __restrict__ eoff, const int* __restrict__ eperm,
                            const int* __restrict__ enode,
                            const float* __restrict__ ax, const float* __restrict__ ae,
                            float* __restrict__ alpha){
    int m = blockIdx.x, t = threadIdx.x;
    int s0 = eoff[m], cnt = eoff[m+1] - s0;
    if (cnt == 0) return;
    __shared__ float red[128];
    float aeh[H];
#pragma unroll
    for (int h = 0; h < H; h++) aeh[h] = ae[m*H + h];
    float lmax[H];
#pragma unroll
    for (int h = 0; h < H; h++) lmax[h] = -1e30f;
    for (int i = t; i < cnt; i += 128){
        int k = eperm[s0+i]; int n = enode[s0+i];
#pragma unroll
        for (int h = 0; h < H; h++){
            float v = lrelu(ax[n*H + h] + aeh[h]);
            alpha[(size_t)k*H + h] = v;
            lmax[h] = fmaxf(lmax[h], v);
        }
    }
    float gmax[H];
#pragma unroll
    for (int h = 0; h < H; h++){
        red[t] = lmax[h]; __syncthreads();
        for (int s = 64; s > 0; s >>= 1){ if (t < s) red[t] = fmaxf(red[t], red[t+s]); __syncthreads(); }
        gmax[h] = red[0]; __syncthreads();
    }
    float lsum[H];
#pragma unroll
    for (int h = 0; h < H; h++) lsum[h] = 0.f;
    for (int i = t; i < cnt; i += 128){
        int k = eperm[s0+i];
#pragma unroll
        for (int h = 0; h < H; h++){
            float ex = __expf(alpha[(size_t)k*H + h] - gmax[h]);
            alpha[(size_t)k*H + h] = ex;
            lsum[h] += ex;
        }
    }
    float ginv[H];
#pragma unroll
    for (int h = 0; h < H; h++){
        red[t] = lsum[h]; __syncthreads();
        for (int s = 64; s > 0; s >>= 1){ if (t < s) red[t] += red[t+s]; __syncthreads(); }
        ginv[h] = 1.f/red[0]; __syncthreads();
    }
    for (int i = t; i < cnt; i += 128){
        int k = eperm[s0+i];
#pragma unroll
        for (int h = 0; h < H; h++) alpha[(size_t)k*H + h] *= ginv[h];
    }
}

// heads=4: 8B loads, 2 rows/iter; eo written as [m][c][h] (head-minor)
__global__ void seg_eo4(const int* __restrict__ eoff, const int* __restrict__ eperm,
                        const int* __restrict__ enode,
                        const float* __restrict__ alpha, const __hip_bfloat16* __restrict__ xt,
                        float* __restrict__ eo){
    int m = blockIdx.x, t = threadIdx.x;   // 256
    int jpar = t >> 7, cq = t & 127;
    int hq = cq >> 5;                      // head of this thread's 4 xt-channels
    int s0 = eoff[m], cnt = eoff[m+1] - s0;
    __shared__ int sn[128];
    __shared__ float sa[128][4];
    __shared__ float comb[256][4];
    float acc[4] = {0.f, 0.f, 0.f, 0.f};
    for (int base = 0; base < cnt; base += 128){
        int i = base + t;
        if (t < 128 && i < cnt){
            sn[t] = enode[s0+i];
            *(float4*)sa[t] = *(const float4*)&alpha[(size_t)eperm[s0+i]*4];
        }
        __syncthreads();
        int lim = min(128, cnt - base);
        for (int j = jpar; j < lim; j += 2){
            const ushort* p = (const ushort*)xt + (size_t)sn[j]*512 + cq*4;
            ushort4 u = *(const ushort4*)p;
            float a = sa[j][hq];
            acc[0] += a*b2f((short)u.x); acc[1] += a*b2f((short)u.y);
            acc[2] += a*b2f((short)u.z); acc[3] += a*b2f((short)u.w);
        }
        __syncthreads();
    }
    comb[t][0] = acc[0]; comb[t][1] = acc[1]; comb[t][2] = acc[2]; comb[t][3] = acc[3];
    __syncthreads();
    if (t < 128){
        float binv = cnt > 0 ? 1.f/(float)cnt : 0.f;
#pragma unroll
        for (int i2 = 0; i2 < 4; i2++){
            int ch = t*4 + i2;
            int h = ch >> 7, c = ch & 127;
            eo[(size_t)m*512 + c*4 + h] = (comb[t][i2] + comb[t+128][i2]) * binv;
        }
    }
}

// heads=1: 8B loads, 4 rows/iter
__global__ void seg_eo1b(const int* __restrict__ eoff, const int* __restrict__ eperm,
                         const int* __restrict__ enode,
                         const float* __restrict__ alpha, const __hip_bfloat16* __restrict__ xt,
                         float* __restrict__ eo){
    int m = blockIdx.x, t = threadIdx.x;   // 128
    int jg = t >> 5, cq = t & 31;
    int s0 = eoff[m], cnt = eoff[m+1] - s0;
    __shared__ int sn[128];
    __shared__ float sa[128];
    __shared__ float4 comb[4][32];
    float4 acc = {0,0,0,0};
    for (int base = 0; base < cnt; base += 128){
        int i = base + t;
        if (i < cnt){
            sn[t] = enode[s0+i];
            sa[t] = alpha[eperm[s0+i]];
        }
        __syncthreads();
        int lim = min(128, cnt - base);
        for (int j = jg; j < lim; j += 4){
            const ushort* p = (const ushort*)xt + (size_t)sn[j]*128 + cq*4;
            ushort4 u = *(const ushort4*)p;
            float a = sa[j];
            acc.x += a*b2f((short)u.x); acc.y += a*b2f((short)u.y);
            acc.z += a*b2f((short)u.z); acc.w += a*b2f((short)u.w);
        }
        __syncthreads();
    }
    comb[jg][cq] = acc;
    __syncthreads();
    if (t < 32){
        float binv = cnt > 0 ? 1.f/(float)cnt : 0.f;
        float4 a = comb[0][t], b = comb[1][t], c = comb[2][t], d = comb[3][t];
        float4 tot = { (a.x+b.x+c.x+d.x)*binv, (a.y+b.y+c.y+d.y)*binv,
                       (a.z+b.z+c.z+d.z)*binv, (a.w+b.w+c.w+d.w)*binv };
        *(float4*)&eo[(size_t)m*128 + t*4] = tot;
    }
}

// heads=4: eo is [m][c][h] -> one float4(alpha) + one float4(eo) per incidence
__global__ void seg_node_out4(const int* __restrict__ noff, const int* __restrict__ nperm,
                              const int* __restrict__ nedge,
                              const float* __restrict__ alpha, const float* __restrict__ eo,
                              const float* __restrict__ hin, const float* __restrict__ bias,
                              float* __restrict__ hout){
    int n = blockIdx.x, c = threadIdx.x;   // 128
    int s0 = noff[n], cnt = noff[n+1] - s0;
    float acc = 0.f;
    for (int i = 0; i < cnt; i++){
        int k = nperm[s0+i]; int e = nedge[s0+i];
        float4 al = *(const float4*)&alpha[(size_t)k*4];
        float4 ev = *(const float4*)&eo[(size_t)e*512 + c*4];
        acc += al.x*ev.x + al.y*ev.y + al.z*ev.z + al.w*ev.w;
    }
    float dinv = cnt > 0 ? 1.f/((float)cnt*4.f) : 0.f;
    hout[(size_t)n*128 + c] = hin[(size_t)n*128 + c] + bias[c] + acc*dinv;
}

__global__ void seg_node_out1(const int* __restrict__ noff, const int* __restrict__ nperm,
                              const int* __restrict__ nedge,
                              const float* __restrict__ alpha, const float* __restrict__ eo,
                              const float* __restrict__ hin, const float* __restrict__ bias,
                              float* __restrict__ hout){
    int n = blockIdx.x, c = threadIdx.x;
    int s0 = noff[n], cnt = noff[n+1] - s0;
    float acc = 0.f;
    for (int i = 0; i < cnt; i++){
        int k = nperm[s0+i]; int e = nedge[s0+i];
        acc += alpha[k]*eo[(size_t)e*128 + c];
    }
    float dinv = cnt > 0 ? 1.f/(float)cnt : 0.f;
    hout[(size_t)n*128 + c] = hin[(size_t)n*128 + c] + bias[c] + acc*dinv;
}

// ---------------------------------------------------------------- launcher
extern "C" void kernel_launch(void* const* d_in, const int* in_sizes, int n_in,
                              void* d_out, int out_size, void* d_ws, size_t ws_size,
                              hipStream_t stream){
    const float* x    = (const float*)d_in[0];
    const int*   he_n = (const int*)  d_in[1];
    const int*   he_e = (const int*)  d_in[2];
    const float* W1   = (const float*)d_in[3];
    const float* b1   = (const float*)d_in[4];
    const float* g1   = (const float*)d_in[5];
    const float* be1  = (const float*)d_in[6];
    const float* Wh1  = (const float*)d_in[7];
    const float* att1 = (const float*)d_in[8];
    const float* bh1  = (const float*)d_in[9];
    const float* g2   = (const float*)d_in[10];
    const float* be2  = (const float*)d_in[11];
    const float* Wh2  = (const float*)d_in[12];
    const float* att2 = (const float*)d_in[13];
    const float* bh2  = (const float*)d_in[14];
    const float* g3   = (const float*)d_in[15];
    const float* be3  = (const float*)d_in[16];
    const float* W3   = (const float*)d_in[17];
    const float* b3   = (const float*)d_in[18];
    const float* g4   = (const float*)d_in[19];
    const float* be4  = (const float*)d_in[20];
    float* out = (float*)d_out;

    char* ws = (char*)d_ws;
    size_t off = 0;
    auto alloc = [&](size_t bytes)->char*{ char* p = ws + off; off += (bytes + 255) & ~(size_t)255; return p; };

    // big region (64 MB): fbuf (final) aliases part (GEMM1) + xt1b (hconv1)
    char* big = alloc((size_t)NN*DIN*2);
    __hip_bfloat16* fbuf = (__hip_bfloat16*)big;
    __hip_bfloat16* part = (__hip_bfloat16*)big;                          // 16 x 2MB = 32MB
    __hip_bfloat16* xt1b = (__hip_bfloat16*)(big + (size_t)16*NN*128*2);  // 9.4MB at +32MB
    __hip_bfloat16* xbuf = (__hip_bfloat16*)alloc((size_t)NN*DIN*2);      // bf16 x (64MB)

    float* hall1  = (float*)alloc((size_t)MALL*128*4);
    float* hall2  = (float*)alloc((size_t)MALL*128*4);
    float* h3     = (float*)alloc((size_t)NN*128*4);
    __hip_bfloat16* xt2b = (__hip_bfloat16*)alloc((size_t)MALL*128*2);
    float* eo     = (float*)alloc((size_t)MME*512*4);
    float* alpha  = (float*)alloc((size_t)NNZK*4*4);
    float* ax     = (float*)alloc((size_t)NN*4*4);
    float* ae     = (float*)alloc((size_t)MME*4*4);
    float* slots  = (float*)alloc((size_t)NSLOT*256*4);
    float* coef   = (float*)alloc(256*4);
    __hip_bfloat16* W1T  = (__hip_bfloat16*)alloc((size_t)128*DIN*2);
    __hip_bfloat16* Wh1T = (__hip_bfloat16*)alloc((size_t)512*128*2);
    __hip_bfloat16* Wh2T = (__hip_bfloat16*)alloc((size_t)128*128*2);
    __hip_bfloat16* W3T  = (__hip_bfloat16*)alloc((size_t)DIN*128*2);
    int* ecnt  = (int*)alloc(MME*4);
    int* ncnt  = (int*)alloc(NN*4);
    int* eoffb = (int*)alloc((MME+1)*4);
    int* ecur  = (int*)alloc(MME*4);
    int* noffb = (int*)alloc((NN+1)*4);
    int* ncur  = (int*)alloc(NN*4);
    int* eperm = (int*)alloc((size_t)NNZK*4);
    int* nperm = (int*)alloc((size_t)NNZK*4);
    int* enode = (int*)alloc((size_t)NNZK*4);
    int* nedge = (int*)alloc((size_t)NNZK*4);

    // ---- x -> bf16 ----
    convert_x<<<2048, 256, 0, stream>>>((const float4*)x, (bf16x8*)xbuf, NN*DIN/8);

    // ---- CSR build ----
    zero_i<<<(MME+NN+255)/256, 256, 0, stream>>>(ecnt, MME+NN);
    count_seg<<<NNZK/256, 256, 0, stream>>>(he_n, he_e, ncnt, ecnt);
    scan2<<<2, 1024, 0, stream>>>(ecnt, eoffb, ecur, ncnt, noffb, ncur);
    fill_both<<<NNZK/256, 256, 0, stream>>>(he_n, he_e, ecur, ncur, eperm, enode, nperm, nedge);

    // ---- all weight converts ----
    wconv_all<<<1104, 256, 0, stream>>>(W1, W1T, Wh1, Wh1T, Wh2, Wh2T, W3, W3T);

    // ---- layer 0: h1 = lrelu(xb @ W1 + b1); BN1 (stats fused in reduce8s) ----
    gemm_bb<<<dim3(1, NN/128, 16), 256, 0, stream>>>(xbuf, W1T, part, NN, 128, DIN, DIN/16);
    zero_f<<<NSLOT, 256, 0, stream>>>(slots, NSLOT*256);
    reduce8s<<<NN*128/4/256, 256, 0, stream>>>(part, b1, hall1, NN*128/4, 16, slots);
    bn_finalize2z<<<1, 128, 0, stream>>>(slots, NSLOT, g1, be1, 1.f/NN, coef);
    bn_apply4<<<1024, 256, 0, stream>>>((float4*)hall1, coef, (size_t)NN*32);

    // ---- hconv1 (heads=4) ----
    seg_sum_edge<<<MME, 128, 0, stream>>>(eoffb, enode, hall1, hall1 + (size_t)NN*128);
    gemm_att<4><<<dim3(4, MALL/128), 256, 0, stream>>>(hall1, Wh1T, xt1b, att1, ax, ae, MALL, 512, 128);
    seg_softmax<4><<<MME, 128, 0, stream>>>(eoffb, eperm, enode, ax, ae, alpha);
    seg_eo4<<<MME, 256, 0, stream>>>(eoffb, eperm, enode, alpha, xt1b, eo);
    seg_node_out4<<<NN, 128, 0, stream>>>(noffb, nperm, nedge, alpha, eo, hall1, bh1, hall2);
    bn_stats_v2<<<256, 256, 0, stream>>>(hall2, slots, NN);
    bn_finalize2z<<<1, 128, 0, stream>>>(slots, NSLOT, g2, be2, 1.f/NN, coef);
    bn_apply4<<<1024, 256, 0, stream>>>((float4*)hall2, coef, (size_t)NN*32);

    // ---- hconv2 (heads=1) ----
    seg_sum_edge<<<MME, 128, 0, stream>>>(eoffb, enode, hall2, hall2 + (size_t)NN*128);
    gemm_att<1><<<dim3(1, MALL/128), 256, 0, stream>>>(hall2, Wh2T, xt2b, att2, ax, ae, MALL, 128, 128);
    seg_softmax<1><<<MME, 128, 0, stream>>>(eoffb, eperm, enode, ax, ae, alpha);
    seg_eo1b<<<MME, 128, 0, stream>>>(eoffb, eperm, enode, alpha, xt2b, eo);
    seg_node_out1<<<NN, 128, 0, stream>>>(noffb, nperm, nedge, alpha, eo, hall2, bh2, h3);

    // ---- BN3: stats only; apply folded into GEMM3 staging ----
    bn_stats_v2<<<256, 256, 0, stream>>>(h3, slots, NN);
    bn_finalize2z<<<1, 128, 0, stream>>>(slots, NSLOT, g3, be3, 1.f/NN, coef);

    // ---- final: out = BN4(x + lrelu(BN3(h3) @ W3 + b3)) ----
    gemm_nt7<<<dim3(DIN/128, NN/128), 256, 0, stream>>>(h3, W3T, fbuf, b3, coef, NN, DIN, 128);
    final_stats<<<2048, 256, 0, stream>>>((const bf16x8*)xbuf, (const bf16x8*)fbuf, slots, NN*DIN/8);
    bn_finalize2z<<<1, 128, 0, stream>>>(slots, NSLOT, g4, be4, 1.f/((float)NN*TT), coef);
    final_apply<<<2048, 256, 0, stream>>>((const bf16x8*)xbuf, (const bf16x8*)fbuf, coef, (float4*)out, NN*DIN/8);
}